// Round 6
// baseline (670.270 us; speedup 1.0000x reference)
//
#include <hip/hip_runtime.h>
#include <stdint.h>

typedef unsigned short u16;   // bf16 bits

#define B_   4
#define N_   4096
#define C_   1024
#define NT_  (B_*N_)          // 16384 rows
#define HW_  64               // H = W = 64

typedef __attribute__((ext_vector_type(8))) short bf16x8;
typedef __attribute__((ext_vector_type(4))) float f32x4;

__device__ __forceinline__ float b2f(u16 s) {
    union { uint32_t u; float f; } x; x.u = ((uint32_t)s) << 16; return x.f;
}
__device__ __forceinline__ u16 f2b(float f) {
    union { float f; uint32_t u; } x; x.f = f;
    uint32_t u = x.u;
    return (u16)((u + 0x7FFFu + ((u >> 16) & 1u)) >> 16);   // RNE
}
__device__ __forceinline__ float lo2f(uint32_t u) {
    union { uint32_t u; float f; } x; x.u = u << 16; return x.f;
}
__device__ __forceinline__ float hi2f(uint32_t u) {
    union { uint32_t u; float f; } x; x.u = u & 0xFFFF0000u; return x.f;
}
__device__ __forceinline__ void unpack8(uint4 v, float* f) {
    f[0] = lo2f(v.x); f[1] = hi2f(v.x); f[2] = lo2f(v.y); f[3] = hi2f(v.y);
    f[4] = lo2f(v.z); f[5] = hi2f(v.z); f[6] = lo2f(v.w); f[7] = hi2f(v.w);
}

// ---------------------------------------------------------------------------
// Input format detector (0 = bf16, 1 = fp32).
// ---------------------------------------------------------------------------
__global__ void detect_fmt(const u16* __restrict__ x, int* __restrict__ flag)
{
    __shared__ int smax[256];
    const int t = threadIdx.x;
    int m = 0;
    for (int i = t; i < 2048; i += 256) {
        int e = (x[2 * i] >> 7) & 0xFF;
        m = m > e ? m : e;
    }
    smax[t] = m;
    __syncthreads();
    for (int s = 128; s > 0; s >>= 1) {
        if (t < s) smax[t] = smax[t] > smax[t + s] ? smax[t] : smax[t + s];
        __syncthreads();
    }
    if (t == 0) flag[0] = (smax[0] >= 0x90) ? 1 : 0;
}

__global__ void zero_f32(float* p, int n) {
    int i = blockIdx.x * 256 + threadIdx.x;
    if (i < n) p[i] = 0.f;
}

// ---------------------------------------------------------------------------
// x (fp32 or bf16 per flag) -> bf16, one streaming pass.
// ---------------------------------------------------------------------------
__global__ __launch_bounds__(256)
void convert_x(const void* __restrict__ x, u16* __restrict__ xb,
               const int* __restrict__ flag)
{
    const int fmt = flag[0];
    const size_t total = (size_t)NT_ * C_ / 8;          // 2,097,152 vec8
    const size_t stride = (size_t)gridDim.x * 256;
    size_t i = (size_t)blockIdx.x * 256 + threadIdx.x;
    if (fmt) {
        for (; i < total; i += stride) {
            const float4* p = (const float4*)x + i * 2;
            float4 a = p[0], b = p[1];
            union { uint4 v; u16 s[8]; } o;
            o.s[0] = f2b(a.x); o.s[1] = f2b(a.y); o.s[2] = f2b(a.z); o.s[3] = f2b(a.w);
            o.s[4] = f2b(b.x); o.s[5] = f2b(b.y); o.s[6] = f2b(b.z); o.s[7] = f2b(b.w);
            ((uint4*)xb)[i] = o.v;
        }
    } else {
        for (; i < total; i += stride)
            ((uint4*)xb)[i] = ((const uint4*)x)[i];
    }
}

// ---------------------------------------------------------------------------
// Weight transpose: WT[n, k] = W[k, col0+n] as bf16. W fmt per flag.
// ---------------------------------------------------------------------------
__global__ __launch_bounds__(256)
void transpose_w(const void* __restrict__ W, u16* __restrict__ WT,
                 const int* __restrict__ flag, int ldw, int col0, int Kdim)
{
    __shared__ u16 tile[64][65];
    const int fmt = flag[0];
    const int n0 = blockIdx.x * 64, k0 = blockIdx.y * 64;
    const int t = threadIdx.x;
    const int c = t & 63, rg = t >> 6;
    #pragma unroll 4
    for (int i = 0; i < 16; ++i) {
        int r = rg * 16 + i;
        size_t gi = (size_t)(k0 + r) * ldw + col0 + n0 + c;
        tile[r][c] = fmt ? f2b(((const float*)W)[gi]) : ((const u16*)W)[gi];
    }
    __syncthreads();
    #pragma unroll 4
    for (int i = 0; i < 16; ++i) {
        int r = rg * 16 + i;
        WT[(size_t)(n0 + r) * Kdim + k0 + c] = tile[c][r];
    }
}

// ---------------------------------------------------------------------------
// MFMA GEMM: C[m, j] = sum_k A[m,k] * BT[j,k]   (BT: n-major bf16)
// 128x128 tile, 4 waves (2x2), 4x4 x mfma_f32_16x16x32_bf16 per wave.
//
// AEXT==0: T3 "minimum 2-phase" schedule (m230: 682 TF at this tile size):
//   - K-loop statically unrolled by 2 so BUFFER INDICES ARE COMPILE-TIME
//     CONSTANTS (a runtime `cur` defeats waitcnt disambiguation -> the
//     backend re-inserts vmcnt(0) before the ds_reads, R5 lesson).
//   - per 32-K tile: STAGE(next buf) -> compute(current buf) ->
//     vmcnt(0) -> ONE s_barrier.  Stage latency hides under compute.
//   - setprio(1) around the MFMA cluster (T5).
//   - barriers are asm volatile("s_barrier":::"memory") (IR fence, R4 fix)
//     bracketed by sched_barrier(0).
// AEXT==1: legacy single-buffer 2-barrier structure (fp32 A support).
// ---------------------------------------------------------------------------
template<int RELU, int BIAS, int AEXT, int CEXT>
__global__ __launch_bounds__(256)
void gemm_mfma(const void* __restrict__ A, const u16* __restrict__ BT,
               void* __restrict__ Cout, const void* __restrict__ bias,
               const int* __restrict__ flag, int K, int ldc)
{
    __shared__ u16 As[2][128 * 32];
    __shared__ u16 Bs[2][128 * 32];
    const int fmt = flag[0];
    const int t    = threadIdx.x;
    const int lane = t & 63;
    const int w    = t >> 6;          // wave 0..3
    const int wm   = w >> 1, wn = w & 1;
    const int quad = lane >> 4;       // 0..3
    const int l16  = lane & 15;

    int bid = blockIdx.y * gridDim.x + blockIdx.x;
    const int nwg = gridDim.x * gridDim.y;
    if ((nwg & 7) == 0)
        bid = (bid & 7) * (nwg >> 3) + (bid >> 3);   // bijective chunked swizzle
    const int j0 = (bid % gridDim.x) * 128;
    const int m0 = (bid / gridDim.x) * 128;

    const int srow = lane >> 2;
    const int gseg = ((lane & 3) ^ ((lane >> 3) & 3)) * 8;

    f32x4 acc[4][4] = {};

    if (AEXT) {
        // -------- legacy path (handles fp32 A; single buffer, __syncthreads) --------
        for (int k0 = 0; k0 < K; k0 += 32) {
            if (fmt) {
                #pragma unroll
                for (int i = 0; i < 2; ++i) {
                    const int r0 = w * 32 + i * 16;
                    const float* gp = (const float*)A + (size_t)(m0 + r0 + srow) * K + k0 + gseg;
                    float4 f0 = *(const float4*)gp;
                    float4 f1 = *(const float4*)(gp + 4);
                    union { bf16x8 v; u16 s[8]; } o;
                    o.s[0] = f2b(f0.x); o.s[1] = f2b(f0.y); o.s[2] = f2b(f0.z); o.s[3] = f2b(f0.w);
                    o.s[4] = f2b(f1.x); o.s[5] = f2b(f1.y); o.s[6] = f2b(f1.z); o.s[7] = f2b(f1.w);
                    *(bf16x8*)&As[0][(r0 + srow) * 32 + (lane & 3) * 8] = o.v;
                }
            } else {
                #pragma unroll
                for (int i = 0; i < 2; ++i) {
                    const int r0 = w * 32 + i * 16;
                    const u16* gp = (const u16*)A + (size_t)(m0 + r0 + srow) * K + k0 + gseg;
                    __builtin_amdgcn_global_load_lds(
                        (const __attribute__((address_space(1))) void*)gp,
                        (__attribute__((address_space(3))) void*)&As[0][r0 * 32], 16, 0, 0);
                }
            }
            #pragma unroll
            for (int i = 0; i < 2; ++i) {
                const int r0 = w * 32 + i * 16;
                const u16* gp = BT + (size_t)(j0 + r0 + srow) * K + k0 + gseg;
                __builtin_amdgcn_global_load_lds(
                    (const __attribute__((address_space(1))) void*)gp,
                    (__attribute__((address_space(3))) void*)&Bs[0][r0 * 32], 16, 0, 0);
            }
            __syncthreads();

            bf16x8 af[4], bfr[4];
            #pragma unroll
            for (int mt = 0; mt < 4; ++mt) {
                const int r = wm * 64 + mt * 16 + l16;
                const int slot = quad ^ ((r >> 1) & 3);
                af[mt] = *(const bf16x8*)&As[0][r * 32 + slot * 8];
            }
            #pragma unroll
            for (int nt = 0; nt < 4; ++nt) {
                const int r = wn * 64 + nt * 16 + l16;
                const int slot = quad ^ ((r >> 1) & 3);
                bfr[nt] = *(const bf16x8*)&Bs[0][r * 32 + slot * 8];
            }
            #pragma unroll
            for (int mt = 0; mt < 4; ++mt)
                #pragma unroll
                for (int nt = 0; nt < 4; ++nt)
                    acc[mt][nt] = __builtin_amdgcn_mfma_f32_16x16x32_bf16(
                        af[mt], bfr[nt], acc[mt][nt], 0, 0, 0);
            __syncthreads();
        }
    } else {
        // -------- T3 minimum 2-phase: static buffers, stage-first, 1 barrier/tile --------
        auto stage = [&](int buf, int k0) {
            #pragma unroll
            for (int i = 0; i < 2; ++i) {
                const int r0 = w * 32 + i * 16;
                const u16* gp = (const u16*)A + (size_t)(m0 + r0 + srow) * K + k0 + gseg;
                __builtin_amdgcn_global_load_lds(
                    (const __attribute__((address_space(1))) void*)gp,
                    (__attribute__((address_space(3))) void*)&As[buf][r0 * 32], 16, 0, 0);
            }
            #pragma unroll
            for (int i = 0; i < 2; ++i) {
                const int r0 = w * 32 + i * 16;
                const u16* gp = BT + (size_t)(j0 + r0 + srow) * K + k0 + gseg;
                __builtin_amdgcn_global_load_lds(
                    (const __attribute__((address_space(1))) void*)gp,
                    (__attribute__((address_space(3))) void*)&Bs[buf][r0 * 32], 16, 0, 0);
            }
        };
        auto compute = [&](int buf) {
            bf16x8 af[4], bfr[4];
            #pragma unroll
            for (int mt = 0; mt < 4; ++mt) {
                const int r = wm * 64 + mt * 16 + l16;
                const int slot = quad ^ ((r >> 1) & 3);
                af[mt] = *(const bf16x8*)&As[buf][r * 32 + slot * 8];
            }
            #pragma unroll
            for (int nt = 0; nt < 4; ++nt) {
                const int r = wn * 64 + nt * 16 + l16;
                const int slot = quad ^ ((r >> 1) & 3);
                bfr[nt] = *(const bf16x8*)&Bs[buf][r * 32 + slot * 8];
            }
            __builtin_amdgcn_s_setprio(1);
            #pragma unroll
            for (int mt = 0; mt < 4; ++mt)
                #pragma unroll
                for (int nt = 0; nt < 4; ++nt)
                    acc[mt][nt] = __builtin_amdgcn_mfma_f32_16x16x32_bf16(
                        af[mt], bfr[nt], acc[mt][nt], 0, 0, 0);
            __builtin_amdgcn_s_setprio(0);
        };
        #define GBAR() do {                                   \
            __builtin_amdgcn_sched_barrier(0);                \
            asm volatile("s_barrier" ::: "memory");           \
            __builtin_amdgcn_sched_barrier(0);                \
        } while (0)

        // prologue: fill buf0 (tile k=0)
        stage(0, 0);
        asm volatile("s_waitcnt vmcnt(0)" ::: "memory");
        GBAR();

        // main loop: two tiles per iteration, buffer indices are literals
        for (int ko = 0; ko + 64 < K; ko += 64) {
            stage(1, ko + 32);                     // prefetch next tile
            compute(0);                            // consume current (hides stage latency)
            asm volatile("s_waitcnt vmcnt(0)" ::: "memory");
            GBAR();                                // buf1 ready; buf0 reads done

            stage(0, ko + 64);
            compute(1);
            asm volatile("s_waitcnt vmcnt(0)" ::: "memory");
            GBAR();                                // buf0 ready; buf1 reads done
        }
        // tail: buf0 holds tile K-64 (staged in last main iter)
        stage(1, K - 32);
        compute(0);
        asm volatile("s_waitcnt vmcnt(0)" ::: "memory");
        GBAR();
        compute(1);
        #undef GBAR
    }

    #pragma unroll
    for (int mt = 0; mt < 4; ++mt) {
        #pragma unroll
        for (int nt = 0; nt < 4; ++nt) {
            const int col = j0 + wn * 64 + nt * 16 + l16;
            float bv = 0.f;
            if (BIAS) bv = fmt ? ((const float*)bias)[col] : b2f(((const u16*)bias)[col]);
            #pragma unroll
            for (int r = 0; r < 4; ++r) {
                const int row = m0 + wm * 64 + mt * 16 + quad * 4 + r;
                float v = acc[mt][nt][r];
                if (BIAS) v += bv;
                if (RELU) v = fmaxf(v, 0.f) + 1e-6f;
                if (CEXT && fmt) ((float*)Cout)[(size_t)row * ldc + col] = v;
                else             ((u16*)Cout)[(size_t)row * ldc + col] = f2b(v);
            }
        }
    }
}

// ---------------------------------------------------------------------------
// Fallback VALU GEMM (proven) — used only if ws_size is too small.
// ---------------------------------------------------------------------------
template<int RELU, int BIAS, int AEXT, int CEXT>
__global__ __launch_bounds__(256)
void gemm_any(const void* __restrict__ A, const void* __restrict__ Bm,
              void* __restrict__ Cout, const void* __restrict__ bias,
              const int* __restrict__ flag,
              int M, int K, int ldb, int bcol0, int ldc)
{
    const int fmt = flag[0];
    __shared__ float As[16][128];
    __shared__ float Bs[16][128];
    const int t  = threadIdx.x;
    const int tx = t & 15, ty = t >> 4;
    const int m0 = blockIdx.y * 128;
    const int j0 = blockIdx.x * 128;
    const int la_row = t >> 1;
    const int la_k   = (t & 1) * 8;
    const int lb_k   = t >> 4;
    const int lb_j   = (t & 15) * 8;

    float acc[8][8];
    #pragma unroll
    for (int i = 0; i < 8; ++i)
        #pragma unroll
        for (int j = 0; j < 8; ++j) acc[i][j] = 0.f;

    for (int k0 = 0; k0 < K; k0 += 16) {
        float af[8], bfv[8];
        if (AEXT && fmt) {
            const float* ap = (const float*)A + (size_t)(m0 + la_row) * K + k0 + la_k;
            float4 a0 = *(const float4*)ap;
            float4 a1 = *(const float4*)(ap + 4);
            af[0] = a0.x; af[1] = a0.y; af[2] = a0.z; af[3] = a0.w;
            af[4] = a1.x; af[5] = a1.y; af[6] = a1.z; af[7] = a1.w;
        } else {
            uint4 av = *(const uint4*)((const u16*)A + (size_t)(m0 + la_row) * K + k0 + la_k);
            unpack8(av, af);
        }
        if (fmt) {
            const float* bp = (const float*)Bm + (size_t)(k0 + lb_k) * ldb + bcol0 + j0 + lb_j;
            float4 b0 = *(const float4*)bp;
            float4 b1 = *(const float4*)(bp + 4);
            bfv[0] = b0.x; bfv[1] = b0.y; bfv[2] = b0.z; bfv[3] = b0.w;
            bfv[4] = b1.x; bfv[5] = b1.y; bfv[6] = b1.z; bfv[7] = b1.w;
        } else {
            uint4 bv = *(const uint4*)((const u16*)Bm + (size_t)(k0 + lb_k) * ldb + bcol0 + j0 + lb_j);
            unpack8(bv, bfv);
        }
        __syncthreads();
        #pragma unroll
        for (int i = 0; i < 8; ++i) As[la_k + i][la_row] = af[i];
        *(float4*)&Bs[lb_k][lb_j]     = make_float4(bfv[0], bfv[1], bfv[2], bfv[3]);
        *(float4*)&Bs[lb_k][lb_j + 4] = make_float4(bfv[4], bfv[5], bfv[6], bfv[7]);
        __syncthreads();
        #pragma unroll
        for (int kk = 0; kk < 16; ++kk) {
            float a[8], b[8];
            *(float4*)&a[0] = *(const float4*)&As[kk][ty * 8];
            *(float4*)&a[4] = *(const float4*)&As[kk][ty * 8 + 4];
            *(float4*)&b[0] = *(const float4*)&Bs[kk][tx * 8];
            *(float4*)&b[4] = *(const float4*)&Bs[kk][tx * 8 + 4];
            #pragma unroll
            for (int i = 0; i < 8; ++i)
                #pragma unroll
                for (int j = 0; j < 8; ++j)
                    acc[i][j] += a[i] * b[j];
        }
    }

    #pragma unroll
    for (int i = 0; i < 8; ++i) {
        const int m = m0 + ty * 8 + i;
        float vals[8];
        #pragma unroll
        for (int j = 0; j < 8; ++j) {
            float v = acc[i][j];
            if (BIAS) {
                const int bi = j0 + tx * 8 + j;
                v += fmt ? ((const float*)bias)[bi] : b2f(((const u16*)bias)[bi]);
            }
            if (RELU) v = fmaxf(v, 0.f) + 1e-6f;
            vals[j] = v;
        }
        if (CEXT && fmt) {
            float* cp = (float*)Cout + (size_t)m * ldc + j0 + tx * 8;
            *(float4*)cp       = make_float4(vals[0], vals[1], vals[2], vals[3]);
            *(float4*)(cp + 4) = make_float4(vals[4], vals[5], vals[6], vals[7]);
        } else {
            union { uint4 v; u16 s[8]; } o;
            #pragma unroll
            for (int j = 0; j < 8; ++j) o.s[j] = f2b(vals[j]);
            *(uint4*)((u16*)Cout + (size_t)m * ldc + j0 + tx * 8) = o.v;
        }
    }
}

// k_mean[b, c] = mean_n k[b, n, c]
__global__ __launch_bounds__(256)
void kmean_kernel(const u16* __restrict__ k, float* __restrict__ km)
{
    const int c  = blockIdx.x * 256 + threadIdx.x;
    const int b  = blockIdx.y;
    const int nc = blockIdx.z;
    const u16* p = k + ((size_t)b * N_ + nc * 256) * C_ + c;
    float s = 0.f;
    for (int n = 0; n < 256; ++n) s += b2f(p[(size_t)n * C_]);
    atomicAdd(&km[b * C_ + c], s * (1.0f / N_));
}

// kvh[bh, d*64+e] += (1/N) * sum_{n in chunk} k*v
__global__ __launch_bounds__(256)
void kv_atomic(const u16* __restrict__ k, const u16* __restrict__ v,
               float* __restrict__ kvh)
{
    __shared__ float kk[4][64];
    __shared__ float vv[4][64];
    const int bh = blockIdx.x;
    const int ch = blockIdx.y;
    const int b = bh >> 4, h = bh & 15;
    const int t = threadIdx.x;
    const int e = t & 63, d0 = (t >> 6) * 16;
    const int lr = t >> 6, lc = t & 63;
    const int n0 = ch * 512;
    float acc[16];
    #pragma unroll
    for (int i = 0; i < 16; ++i) acc[i] = 0.f;

    for (int nb = 0; nb < 512; nb += 4) {
        size_t base = ((size_t)(b * N_ + n0 + nb + lr)) * C_ + h * 64 + lc;
        float kf = b2f(k[base]);
        float vf = b2f(v[base]);
        __syncthreads();
        kk[lr][lc] = kf;
        vv[lr][lc] = vf;
        __syncthreads();
        #pragma unroll
        for (int r = 0; r < 4; ++r) {
            float ve = vv[r][e];
            #pragma unroll
            for (int i = 0; i < 16; ++i) acc[i] += kk[r][d0 + i] * ve;
        }
    }
    float* dst = kvh + (size_t)bh * 4096;
    #pragma unroll
    for (int i = 0; i < 16; ++i)
        atomicAdd(&dst[(d0 + i) * 64 + e], acc[i] * (1.0f / N_));
}

// ---------------------------------------------------------------------------
// att: y = (q @ KV_h) * z.   kv column e held in 64 VGPRs (reused over all
// 16 rows) -> inner loop is wave-uniform ds_read_b128 of qs + VALU FMA.
// ---------------------------------------------------------------------------
__global__ __launch_bounds__(256)
void att_kernel(const u16* __restrict__ q, const float* __restrict__ kvh,
                const float* __restrict__ kmean, u16* __restrict__ y)
{
    __shared__ float kvs[64 * 64];
    __shared__ float qs[64 * 68];     // 68-float pitch: 272 B, 16B-aligned rows
    __shared__ float kmv[64];
    __shared__ float zs[64];
    const int bh = blockIdx.y;
    const int b = bh >> 4, h = bh & 15;
    const int n0 = blockIdx.x * 64;
    const int t = threadIdx.x;
    const int e = t & 63, rg = t >> 6;

    // cooperative loads (vectorized)
    const float4* kvsrc4 = (const float4*)(kvh + (size_t)bh * 4096);
    #pragma unroll
    for (int i = 0; i < 4; ++i)
        *(float4*)&kvs[(i * 256 + t) * 4] = kvsrc4[i * 256 + t];
    if (t < 64) kmv[t] = kmean[b * C_ + h * 64 + t];
    #pragma unroll
    for (int ii = 0; ii < 2; ++ii) {
        int i = ii * 256 + t;               // 512 x uint4 = 4096 u16
        int r = i >> 3, c8 = (i & 7) * 8;
        uint4 v = *(const uint4*)&q[((size_t)(b * N_ + n0 + r)) * C_ + h * 64 + c8];
        float f[8];
        unpack8(v, f);
        #pragma unroll
        for (int j = 0; j < 8; ++j) qs[r * 68 + c8 + j] = f[j];
    }
    __syncthreads();

    // kv column e -> registers (stride-1 across lanes: conflict-free)
    float kvr[64];
    #pragma unroll
    for (int d = 0; d < 64; ++d) kvr[d] = kvs[d * 64 + e];

    if (t < 64) {
        float s = 1e-6f;
        #pragma unroll
        for (int d = 0; d < 64; ++d) s += qs[t * 68 + d] * kmv[d];
        zs[t] = 1.0f / s;
    }
    __syncthreads();

    for (int rr = 0; rr < 16; ++rr) {
        int r = rg * 16 + rr;
        float acc = 0.f;
        #pragma unroll
        for (int d = 0; d < 64; ++d) acc += qs[r * 68 + d] * kvr[d];
        y[((size_t)(b * N_ + n0 + r)) * C_ + h * 64 + e] = f2b(acc * zs[r]);
    }
}

// ---------------------------------------------------------------------------
// Depthwise 5x5 conv over v, add into y — channel-vectorized (uint4 = 8 bf16).
// ---------------------------------------------------------------------------
__global__ __launch_bounds__(256)
void conv_add(const u16* __restrict__ v, const void* __restrict__ w,
              const void* __restrict__ wb, u16* __restrict__ y,
              const int* __restrict__ flag)
{
    __shared__ float wt[25][64];
    __shared__ float bl[64];
    const int fmt = flag[0];
    const int t = threadIdx.x;
    for (int i = t; i < 1600; i += 256) {
        const int tap = i >> 6, c = i & 63;
        const int src = c * 25 + tap;
        wt[tap][c] = fmt ? ((const float*)w)[src] : b2f(((const u16*)w)[src]);
    }
    if (t < 64)
        bl[t] = fmt ? ((const float*)wb)[t] : b2f(((const u16*)wb)[t]);
    __syncthreads();

    const size_t gid = (size_t)blockIdx.x * 256 + t;   // 0 .. 2,097,151
    const int cg = (int)(gid & 127);                   // channel-group (8 ch)
    const int n  = (int)((gid >> 7) & 4095);           // pixel (wave-uniform)
    const int b  = (int)(gid >> 19);
    const int c0 = cg * 8;
    const int cb = c0 & 63;                            // weight channel base
    const int yp = n >> 6, xp = n & 63;

    float acc[8];
    #pragma unroll
    for (int j = 0; j < 8; ++j) acc[j] = bl[cb + j];

    const u16* vbase = v + (size_t)b * N_ * C_ + c0;
    #pragma unroll
    for (int dy = 0; dy < 5; ++dy) {
        const int yy = yp + dy - 2;
        if (yy < 0 || yy >= HW_) continue;
        #pragma unroll
        for (int dx = 0; dx < 5; ++dx) {
            const int xx = xp + dx - 2;
            if (xx < 0 || xx >= HW_) continue;
            uint4 pv = *(const uint4*)(vbase + (size_t)(yy * HW_ + xx) * C_);
            float f[8];
            unpack8(pv, f);
            const int tap = dy * 5 + dx;
            float4 w0 = *(const float4*)&wt[tap][cb];
            float4 w1 = *(const float4*)&wt[tap][cb + 4];
            acc[0] += w0.x * f[0]; acc[1] += w0.y * f[1];
            acc[2] += w0.z * f[2]; acc[3] += w0.w * f[3];
            acc[4] += w1.x * f[4]; acc[5] += w1.y * f[5];
            acc[6] += w1.z * f[6]; acc[7] += w1.w * f[7];
        }
    }

    uint4 yv = *(const uint4*)(y + gid * 8);
    float yf[8];
    unpack8(yv, yf);
    union { uint4 v4; u16 s[8]; } o;
    #pragma unroll
    for (int j = 0; j < 8; ++j) o.s[j] = f2b(yf[j] + acc[j]);
    *(uint4*)(y + gid * 8) = o.v4;
}

extern "C" void kernel_launch(void* const* d_in, const int* in_sizes, int n_in,
                              void* d_out, int out_size, void* d_ws, size_t ws_size,
                              hipStream_t stream)
{
    const void* x     = d_in[0];
    const void* Wq    = d_in[1];
    const void* Wkv   = d_in[2];
    const void* Wproj = d_in[3];
    const void* bproj = d_in[4];
    const void* dwc_w = d_in[5];
    const void* dwc_b = d_in[6];

    char* ws = (char*)d_ws;
    const size_t MI = 1024 * 1024;
    const size_t NEED_FAST = 35 * MI + 17 * 1024;
    const size_t OUT_F32   = (size_t)NT_ * C_ * sizeof(float);   // 64 MB

    if (ws_size >= NEED_FAST && (size_t)out_size >= OUT_F32) {
        // ---- fastest path: x pre-converted to bf16 -> all GEMMs use the
        //      static-2-phase pipelined path (AEXT=0). ----
        u16*   vbuf  = (u16*)ws;
        u16*   WT    = (u16*)(ws + 32 * MI);
        float* kvh   = (float*)(ws + 34 * MI);
        float* kmean = (float*)(ws + 35 * MI);
        int*   flag  = (int*)(ws + 35 * MI + 16 * 1024);
        u16*   xb    = (u16*)d_out;                       // lower 32 MB of out
        u16*   kq    = (u16*)d_out + (size_t)NT_ * C_;    // upper 32 MB of out
        u16*   ybuf  = (u16*)ws;

        detect_fmt<<<1, 256, 0, stream>>>((const u16*)x, flag);
        zero_f32<<<dim3(1040), 256, 0, stream>>>(kvh, 266240);   // kvh + kmean contiguous
        convert_x<<<dim3(2048), 256, 0, stream>>>(x, xb, flag);

        // v = xb @ Wkv[:, C:]
        transpose_w<<<dim3(16, 16), 256, 0, stream>>>(Wkv, WT, flag, 2 * C_, C_, C_);
        gemm_mfma<0, 0, 0, 0><<<dim3(8, 128), 256, 0, stream>>>(xb, WT, vbuf, nullptr, flag, C_, C_);
        // k = relu(xb @ Wkv[:, :C]) + eps
        transpose_w<<<dim3(16, 16), 256, 0, stream>>>(Wkv, WT, flag, 2 * C_, 0, C_);
        gemm_mfma<1, 0, 0, 0><<<dim3(8, 128), 256, 0, stream>>>(xb, WT, kq, nullptr, flag, C_, C_);

        kmean_kernel<<<dim3(4, B_, 16), 256, 0, stream>>>(kq, kmean);
        kv_atomic<<<dim3(64, 8), 256, 0, stream>>>(kq, vbuf, kvh);

        // q = relu(xb @ Wq) + eps  (overwrites k; k dead, xb disjoint)
        transpose_w<<<dim3(16, 16), 256, 0, stream>>>(Wq, WT, flag, C_, 0, C_);
        gemm_mfma<1, 0, 0, 0><<<dim3(8, 128), 256, 0, stream>>>(xb, WT, kq, nullptr, flag, C_, C_);

        att_kernel<<<dim3(64, 64), 256, 0, stream>>>(kq, kvh, kmean, kq);
        conv_add<<<dim3(8192), 256, 0, stream>>>(vbuf, dwc_w, dwc_b, kq, flag);

        // move y into ws (v dead), then out = y @ Wproj + bproj (fp32 over all of d_out)
        hipMemcpyAsync(ws, kq, (size_t)NT_ * C_ * sizeof(u16), hipMemcpyDeviceToDevice, stream);
        transpose_w<<<dim3(16, 16), 256, 0, stream>>>(Wproj, WT, flag, C_, 0, C_);
        gemm_mfma<0, 1, 0, 1><<<dim3(8, 128), 256, 0, stream>>>(ybuf, WT, d_out, bproj, flag, C_, C_);
    } else if (ws_size >= NEED_FAST) {
        // ---- previous fast path (MFMA, fp32 A staged in-loop; AEXT=1 legacy) ----
        u16*   vbuf  = (u16*)ws;
        u16*   WT    = (u16*)(ws + 32 * MI);
        float* kvh   = (float*)(ws + 34 * MI);
        float* kmean = (float*)(ws + 35 * MI);
        int*   flag  = (int*)(ws + 35 * MI + 16 * 1024);
        u16*   kq    = (u16*)d_out;
        u16*   ybuf  = (u16*)ws;

        detect_fmt<<<1, 256, 0, stream>>>((const u16*)x, flag);
        zero_f32<<<dim3(1040), 256, 0, stream>>>(kvh, 266240);

        transpose_w<<<dim3(16, 16), 256, 0, stream>>>(Wkv, WT, flag, 2 * C_, C_, C_);
        gemm_mfma<0, 0, 1, 0><<<dim3(8, 128), 256, 0, stream>>>(x, WT, vbuf, nullptr, flag, C_, C_);
        transpose_w<<<dim3(16, 16), 256, 0, stream>>>(Wkv, WT, flag, 2 * C_, 0, C_);
        gemm_mfma<1, 0, 1, 0><<<dim3(8, 128), 256, 0, stream>>>(x, WT, kq, nullptr, flag, C_, C_);

        kmean_kernel<<<dim3(4, B_, 16), 256, 0, stream>>>(kq, kmean);
        kv_atomic<<<dim3(64, 8), 256, 0, stream>>>(kq, vbuf, kvh);

        transpose_w<<<dim3(16, 16), 256, 0, stream>>>(Wq, WT, flag, C_, 0, C_);
        gemm_mfma<1, 0, 1, 0><<<dim3(8, 128), 256, 0, stream>>>(x, WT, kq, nullptr, flag, C_, C_);

        att_kernel<<<dim3(64, 64), 256, 0, stream>>>(kq, kvh, kmean, kq);
        conv_add<<<dim3(8192), 256, 0, stream>>>(vbuf, dwc_w, dwc_b, kq, flag);

        hipMemcpyAsync(ws, d_out, (size_t)NT_ * C_ * sizeof(u16), hipMemcpyDeviceToDevice, stream);
        transpose_w<<<dim3(16, 16), 256, 0, stream>>>(Wproj, WT, flag, C_, 0, C_);
        gemm_mfma<0, 1, 0, 1><<<dim3(8, 128), 256, 0, stream>>>(ybuf, WT, d_out, bproj, flag, C_, C_);
    } else {
        // ---- fallback path (proven) ----
        u16*   vbuf  = (u16*)ws;
        float* kmean = (float*)(ws + 32 * MI);
        float* kvh   = (float*)(ws + 32 * MI + 16 * 1024);
        int*   flag  = (int*)(ws + 32 * MI + 16 * 1024 + 1 * MI);
        u16*   kq    = (u16*)d_out;
        u16*   ybuf  = (u16*)ws;

        detect_fmt<<<1, 256, 0, stream>>>((const u16*)x, flag);
        zero_f32<<<dim3(1040), 256, 0, stream>>>(kmean, 266240);

        gemm_any<0, 0, 1, 0><<<dim3(8, 128), 256, 0, stream>>>(x, Wkv, vbuf, nullptr, flag, NT_, C_, 2 * C_, C_, C_);
        gemm_any<1, 0, 1, 0><<<dim3(8, 128), 256, 0, stream>>>(x, Wkv, kq,   nullptr, flag, NT_, C_, 2 * C_, 0,  C_);

        kmean_kernel<<<dim3(4, B_, 16), 256, 0, stream>>>(kq, kmean);
        kv_atomic<<<dim3(64, 8), 256, 0, stream>>>(kq, vbuf, kvh);

        gemm_any<1, 0, 1, 0><<<dim3(8, 128), 256, 0, stream>>>(x, Wq, kq, nullptr, flag, NT_, C_, C_, 0, C_);

        att_kernel<<<dim3(64, 64), 256, 0, stream>>>(kq, kvh, kmean, kq);
        conv_add<<<dim3(8192), 256, 0, stream>>>(vbuf, dwc_w, dwc_b, kq, flag);

        hipMemcpyAsync(ws, d_out, (size_t)NT_ * C_ * sizeof(u16), hipMemcpyDeviceToDevice, stream);
        gemm_any<0, 1, 0, 1><<<dim3(8, 128), 256, 0, stream>>>(ybuf, Wproj, d_out, bproj, flag, NT_, C_, C_, 0, C_);
    }
}

// Round 7
// 661.228 us; speedup vs baseline: 1.0137x; 1.0137x over previous
//
#include <hip/hip_runtime.h>
#include <stdint.h>

typedef unsigned short u16;   // bf16 bits

#define B_   4
#define N_   4096
#define C_   1024
#define NT_  (B_*N_)          // 16384 rows
#define HW_  64               // H = W = 64

typedef __attribute__((ext_vector_type(8))) short bf16x8;
typedef __attribute__((ext_vector_type(4))) float f32x4;

__device__ __forceinline__ float b2f(u16 s) {
    union { uint32_t u; float f; } x; x.u = ((uint32_t)s) << 16; return x.f;
}
__device__ __forceinline__ u16 f2b(float f) {
    union { float f; uint32_t u; } x; x.f = f;
    uint32_t u = x.u;
    return (u16)((u + 0x7FFFu + ((u >> 16) & 1u)) >> 16);   // RNE
}
__device__ __forceinline__ float lo2f(uint32_t u) {
    union { uint32_t u; float f; } x; x.u = u << 16; return x.f;
}
__device__ __forceinline__ float hi2f(uint32_t u) {
    union { uint32_t u; float f; } x; x.u = u & 0xFFFF0000u; return x.f;
}
__device__ __forceinline__ void unpack8(uint4 v, float* f) {
    f[0] = lo2f(v.x); f[1] = hi2f(v.x); f[2] = lo2f(v.y); f[3] = hi2f(v.y);
    f[4] = lo2f(v.z); f[5] = hi2f(v.z); f[6] = lo2f(v.w); f[7] = hi2f(v.w);
}

// ---------------------------------------------------------------------------
// Input format detector (0 = bf16, 1 = fp32).
// ---------------------------------------------------------------------------
__global__ void detect_fmt(const u16* __restrict__ x, int* __restrict__ flag)
{
    __shared__ int smax[256];
    const int t = threadIdx.x;
    int m = 0;
    for (int i = t; i < 2048; i += 256) {
        int e = (x[2 * i] >> 7) & 0xFF;
        m = m > e ? m : e;
    }
    smax[t] = m;
    __syncthreads();
    for (int s = 128; s > 0; s >>= 1) {
        if (t < s) smax[t] = smax[t] > smax[t + s] ? smax[t] : smax[t + s];
        __syncthreads();
    }
    if (t == 0) flag[0] = (smax[0] >= 0x90) ? 1 : 0;
}

__global__ void zero_f32(float* p, int n) {
    int i = blockIdx.x * 256 + threadIdx.x;
    if (i < n) p[i] = 0.f;
}

// ---------------------------------------------------------------------------
// x (fp32 or bf16 per flag) -> bf16, one streaming pass.
// ---------------------------------------------------------------------------
__global__ __launch_bounds__(256)
void convert_x(const void* __restrict__ x, u16* __restrict__ xb,
               const int* __restrict__ flag)
{
    const int fmt = flag[0];
    const size_t total = (size_t)NT_ * C_ / 8;          // 2,097,152 vec8
    const size_t stride = (size_t)gridDim.x * 256;
    size_t i = (size_t)blockIdx.x * 256 + threadIdx.x;
    if (fmt) {
        for (; i < total; i += stride) {
            const float4* p = (const float4*)x + i * 2;
            float4 a = p[0], b = p[1];
            union { uint4 v; u16 s[8]; } o;
            o.s[0] = f2b(a.x); o.s[1] = f2b(a.y); o.s[2] = f2b(a.z); o.s[3] = f2b(a.w);
            o.s[4] = f2b(b.x); o.s[5] = f2b(b.y); o.s[6] = f2b(b.z); o.s[7] = f2b(b.w);
            ((uint4*)xb)[i] = o.v;
        }
    } else {
        for (; i < total; i += stride)
            ((uint4*)xb)[i] = ((const uint4*)x)[i];
    }
}

// ---------------------------------------------------------------------------
// Weight transpose: WT[n, k] = W[k, col0+n] as bf16. W fmt per flag.
// ---------------------------------------------------------------------------
__global__ __launch_bounds__(256)
void transpose_w(const void* __restrict__ W, u16* __restrict__ WT,
                 const int* __restrict__ flag, int ldw, int col0, int Kdim)
{
    __shared__ u16 tile[64][65];
    const int fmt = flag[0];
    const int n0 = blockIdx.x * 64, k0 = blockIdx.y * 64;
    const int t = threadIdx.x;
    const int c = t & 63, rg = t >> 6;
    #pragma unroll 4
    for (int i = 0; i < 16; ++i) {
        int r = rg * 16 + i;
        size_t gi = (size_t)(k0 + r) * ldw + col0 + n0 + c;
        tile[r][c] = fmt ? f2b(((const float*)W)[gi]) : ((const u16*)W)[gi];
    }
    __syncthreads();
    #pragma unroll 4
    for (int i = 0; i < 16; ++i) {
        int r = rg * 16 + i;
        WT[(size_t)(n0 + r) * Kdim + k0 + c] = tile[c][r];
    }
}

// ---------------------------------------------------------------------------
// MFMA GEMM: C[m, j] = sum_k A[m,k] * BT[j,k]   (BT: n-major bf16)
// 128x128 tile, 4 waves (2x2), 4x4 x mfma_f32_16x16x32_bf16 per wave.
//
// AEXT==0: ring-4 deep pipeline (R6 lesson: 2-deep ≈ 1-deep here because
//   effective load latency under full-machine burst is ~2500-3000 cyc vs
//   ~600 cyc compute/step; need >=3 tiles in flight to amortize).
//   - 4 LDS buffers; all buffer indices are compile-time literals.
//   - per step t: stage(buf (t+3)%4, tile t+3) -> vmcnt(12) (waits ONLY the
//     oldest tile's 4 loads; 12 newer stay in flight) -> barrier ->
//     compute(buf t%4) -> barrier.  Tail peels vmcnt(8)/(4)/(0).
//   - buffer reuse (stage of buf read at step t-1) is issued only after the
//     post-compute barrier of step t-1 -> no timing assumption.
//   - barriers are asm volatile("s_barrier":::"memory") (R4: IR fence)
//     bracketed by sched_barrier(0); setprio(1) around MFMA cluster.
//   REQUIRES: K multiple of 128 (all call sites use K=1024).
// AEXT==1: legacy single-buffer 2-barrier structure (fp32 A support).
// ---------------------------------------------------------------------------
template<int RELU, int BIAS, int AEXT, int CEXT>
__global__ __launch_bounds__(256)
void gemm_mfma(const void* __restrict__ A, const u16* __restrict__ BT,
               void* __restrict__ Cout, const void* __restrict__ bias,
               const int* __restrict__ flag, int K, int ldc)
{
    __shared__ u16 As[AEXT ? 1 : 4][128 * 32];
    __shared__ u16 Bs[AEXT ? 1 : 4][128 * 32];
    const int fmt = flag[0];
    const int t    = threadIdx.x;
    const int lane = t & 63;
    const int w    = t >> 6;          // wave 0..3
    const int wm   = w >> 1, wn = w & 1;
    const int quad = lane >> 4;       // 0..3
    const int l16  = lane & 15;

    int bid = blockIdx.y * gridDim.x + blockIdx.x;
    const int nwg = gridDim.x * gridDim.y;
    if ((nwg & 7) == 0)
        bid = (bid & 7) * (nwg >> 3) + (bid >> 3);   // bijective chunked swizzle
    const int j0 = (bid % gridDim.x) * 128;
    const int m0 = (bid / gridDim.x) * 128;

    const int srow = lane >> 2;
    const int gseg = ((lane & 3) ^ ((lane >> 3) & 3)) * 8;

    f32x4 acc[4][4] = {};

    if (AEXT) {
        // -------- legacy path (handles fp32 A; single buffer, __syncthreads) --------
        for (int k0 = 0; k0 < K; k0 += 32) {
            if (fmt) {
                #pragma unroll
                for (int i = 0; i < 2; ++i) {
                    const int r0 = w * 32 + i * 16;
                    const float* gp = (const float*)A + (size_t)(m0 + r0 + srow) * K + k0 + gseg;
                    float4 f0 = *(const float4*)gp;
                    float4 f1 = *(const float4*)(gp + 4);
                    union { bf16x8 v; u16 s[8]; } o;
                    o.s[0] = f2b(f0.x); o.s[1] = f2b(f0.y); o.s[2] = f2b(f0.z); o.s[3] = f2b(f0.w);
                    o.s[4] = f2b(f1.x); o.s[5] = f2b(f1.y); o.s[6] = f2b(f1.z); o.s[7] = f2b(f1.w);
                    *(bf16x8*)&As[0][(r0 + srow) * 32 + (lane & 3) * 8] = o.v;
                }
            } else {
                #pragma unroll
                for (int i = 0; i < 2; ++i) {
                    const int r0 = w * 32 + i * 16;
                    const u16* gp = (const u16*)A + (size_t)(m0 + r0 + srow) * K + k0 + gseg;
                    __builtin_amdgcn_global_load_lds(
                        (const __attribute__((address_space(1))) void*)gp,
                        (__attribute__((address_space(3))) void*)&As[0][r0 * 32], 16, 0, 0);
                }
            }
            #pragma unroll
            for (int i = 0; i < 2; ++i) {
                const int r0 = w * 32 + i * 16;
                const u16* gp = BT + (size_t)(j0 + r0 + srow) * K + k0 + gseg;
                __builtin_amdgcn_global_load_lds(
                    (const __attribute__((address_space(1))) void*)gp,
                    (__attribute__((address_space(3))) void*)&Bs[0][r0 * 32], 16, 0, 0);
            }
            __syncthreads();

            bf16x8 af[4], bfr[4];
            #pragma unroll
            for (int mt = 0; mt < 4; ++mt) {
                const int r = wm * 64 + mt * 16 + l16;
                const int slot = quad ^ ((r >> 1) & 3);
                af[mt] = *(const bf16x8*)&As[0][r * 32 + slot * 8];
            }
            #pragma unroll
            for (int nt = 0; nt < 4; ++nt) {
                const int r = wn * 64 + nt * 16 + l16;
                const int slot = quad ^ ((r >> 1) & 3);
                bfr[nt] = *(const bf16x8*)&Bs[0][r * 32 + slot * 8];
            }
            #pragma unroll
            for (int mt = 0; mt < 4; ++mt)
                #pragma unroll
                for (int nt = 0; nt < 4; ++nt)
                    acc[mt][nt] = __builtin_amdgcn_mfma_f32_16x16x32_bf16(
                        af[mt], bfr[nt], acc[mt][nt], 0, 0, 0);
            __syncthreads();
        }
    } else {
        // -------- ring-4 counted-vmcnt pipeline (A, B both bf16) --------
        auto stage = [&](int buf, int tile) {
            const int kk = tile * 32;
            #pragma unroll
            for (int i = 0; i < 2; ++i) {
                const int r0 = w * 32 + i * 16;
                const u16* gp = (const u16*)A + (size_t)(m0 + r0 + srow) * K + kk + gseg;
                __builtin_amdgcn_global_load_lds(
                    (const __attribute__((address_space(1))) void*)gp,
                    (__attribute__((address_space(3))) void*)&As[buf][r0 * 32], 16, 0, 0);
            }
            #pragma unroll
            for (int i = 0; i < 2; ++i) {
                const int r0 = w * 32 + i * 16;
                const u16* gp = BT + (size_t)(j0 + r0 + srow) * K + kk + gseg;
                __builtin_amdgcn_global_load_lds(
                    (const __attribute__((address_space(1))) void*)gp,
                    (__attribute__((address_space(3))) void*)&Bs[buf][r0 * 32], 16, 0, 0);
            }
        };
        auto compute = [&](int buf) {
            bf16x8 af[4], bfr[4];
            #pragma unroll
            for (int mt = 0; mt < 4; ++mt) {
                const int r = wm * 64 + mt * 16 + l16;
                const int slot = quad ^ ((r >> 1) & 3);
                af[mt] = *(const bf16x8*)&As[buf][r * 32 + slot * 8];
            }
            #pragma unroll
            for (int nt = 0; nt < 4; ++nt) {
                const int r = wn * 64 + nt * 16 + l16;
                const int slot = quad ^ ((r >> 1) & 3);
                bfr[nt] = *(const bf16x8*)&Bs[buf][r * 32 + slot * 8];
            }
            __builtin_amdgcn_s_setprio(1);
            #pragma unroll
            for (int mt = 0; mt < 4; ++mt)
                #pragma unroll
                for (int nt = 0; nt < 4; ++nt)
                    acc[mt][nt] = __builtin_amdgcn_mfma_f32_16x16x32_bf16(
                        af[mt], bfr[nt], acc[mt][nt], 0, 0, 0);
            __builtin_amdgcn_s_setprio(0);
        };
        #define GBAR() do {                                   \
            __builtin_amdgcn_sched_barrier(0);                \
            asm volatile("s_barrier" ::: "memory");           \
            __builtin_amdgcn_sched_barrier(0);                \
        } while (0)

        const int nsteps = K >> 5;        // 32-wide K tiles; nsteps % 4 == 0
        // prologue: 3 tiles in flight (12 loads/wave)
        stage(0, 0); stage(1, 1); stage(2, 2);

        int tt = 0;
        for (; tt + 4 < nsteps; tt += 4) {
            stage(3, tt + 3);
            asm volatile("s_waitcnt vmcnt(12)" ::: "memory");
            GBAR(); compute(0); GBAR();
            stage(0, tt + 4);
            asm volatile("s_waitcnt vmcnt(12)" ::: "memory");
            GBAR(); compute(1); GBAR();
            stage(1, tt + 5);
            asm volatile("s_waitcnt vmcnt(12)" ::: "memory");
            GBAR(); compute(2); GBAR();
            stage(2, tt + 6);
            asm volatile("s_waitcnt vmcnt(12)" ::: "memory");
            GBAR(); compute(3); GBAR();
        }
        // tail: tt == nsteps-4; stage last tile, then drain 12 -> 8 -> 4 -> 0
        stage(3, tt + 3);
        asm volatile("s_waitcnt vmcnt(12)" ::: "memory");
        GBAR(); compute(0); GBAR();
        asm volatile("s_waitcnt vmcnt(8)" ::: "memory");
        GBAR(); compute(1); GBAR();
        asm volatile("s_waitcnt vmcnt(4)" ::: "memory");
        GBAR(); compute(2); GBAR();
        asm volatile("s_waitcnt vmcnt(0)" ::: "memory");
        GBAR(); compute(3);
        #undef GBAR
    }

    #pragma unroll
    for (int mt = 0; mt < 4; ++mt) {
        #pragma unroll
        for (int nt = 0; nt < 4; ++nt) {
            const int col = j0 + wn * 64 + nt * 16 + l16;
            float bv = 0.f;
            if (BIAS) bv = fmt ? ((const float*)bias)[col] : b2f(((const u16*)bias)[col]);
            #pragma unroll
            for (int r = 0; r < 4; ++r) {
                const int row = m0 + wm * 64 + mt * 16 + quad * 4 + r;
                float v = acc[mt][nt][r];
                if (BIAS) v += bv;
                if (RELU) v = fmaxf(v, 0.f) + 1e-6f;
                if (CEXT && fmt) ((float*)Cout)[(size_t)row * ldc + col] = v;
                else             ((u16*)Cout)[(size_t)row * ldc + col] = f2b(v);
            }
        }
    }
}

// ---------------------------------------------------------------------------
// Fallback VALU GEMM (proven) — used only if ws_size is too small.
// ---------------------------------------------------------------------------
template<int RELU, int BIAS, int AEXT, int CEXT>
__global__ __launch_bounds__(256)
void gemm_any(const void* __restrict__ A, const void* __restrict__ Bm,
              void* __restrict__ Cout, const void* __restrict__ bias,
              const int* __restrict__ flag,
              int M, int K, int ldb, int bcol0, int ldc)
{
    const int fmt = flag[0];
    __shared__ float As[16][128];
    __shared__ float Bs[16][128];
    const int t  = threadIdx.x;
    const int tx = t & 15, ty = t >> 4;
    const int m0 = blockIdx.y * 128;
    const int j0 = blockIdx.x * 128;
    const int la_row = t >> 1;
    const int la_k   = (t & 1) * 8;
    const int lb_k   = t >> 4;
    const int lb_j   = (t & 15) * 8;

    float acc[8][8];
    #pragma unroll
    for (int i = 0; i < 8; ++i)
        #pragma unroll
        for (int j = 0; j < 8; ++j) acc[i][j] = 0.f;

    for (int k0 = 0; k0 < K; k0 += 16) {
        float af[8], bfv[8];
        if (AEXT && fmt) {
            const float* ap = (const float*)A + (size_t)(m0 + la_row) * K + k0 + la_k;
            float4 a0 = *(const float4*)ap;
            float4 a1 = *(const float4*)(ap + 4);
            af[0] = a0.x; af[1] = a0.y; af[2] = a0.z; af[3] = a0.w;
            af[4] = a1.x; af[5] = a1.y; af[6] = a1.z; af[7] = a1.w;
        } else {
            uint4 av = *(const uint4*)((const u16*)A + (size_t)(m0 + la_row) * K + k0 + la_k);
            unpack8(av, af);
        }
        if (fmt) {
            const float* bp = (const float*)Bm + (size_t)(k0 + lb_k) * ldb + bcol0 + j0 + lb_j;
            float4 b0 = *(const float4*)bp;
            float4 b1 = *(const float4*)(bp + 4);
            bfv[0] = b0.x; bfv[1] = b0.y; bfv[2] = b0.z; bfv[3] = b0.w;
            bfv[4] = b1.x; bfv[5] = b1.y; bfv[6] = b1.z; bfv[7] = b1.w;
        } else {
            uint4 bv = *(const uint4*)((const u16*)Bm + (size_t)(k0 + lb_k) * ldb + bcol0 + j0 + lb_j);
            unpack8(bv, bfv);
        }
        __syncthreads();
        #pragma unroll
        for (int i = 0; i < 8; ++i) As[la_k + i][la_row] = af[i];
        *(float4*)&Bs[lb_k][lb_j]     = make_float4(bfv[0], bfv[1], bfv[2], bfv[3]);
        *(float4*)&Bs[lb_k][lb_j + 4] = make_float4(bfv[4], bfv[5], bfv[6], bfv[7]);
        __syncthreads();
        #pragma unroll
        for (int kk = 0; kk < 16; ++kk) {
            float a[8], b[8];
            *(float4*)&a[0] = *(const float4*)&As[kk][ty * 8];
            *(float4*)&a[4] = *(const float4*)&As[kk][ty * 8 + 4];
            *(float4*)&b[0] = *(const float4*)&Bs[kk][tx * 8];
            *(float4*)&b[4] = *(const float4*)&Bs[kk][tx * 8 + 4];
            #pragma unroll
            for (int i = 0; i < 8; ++i)
                #pragma unroll
                for (int j = 0; j < 8; ++j)
                    acc[i][j] += a[i] * b[j];
        }
    }

    #pragma unroll
    for (int i = 0; i < 8; ++i) {
        const int m = m0 + ty * 8 + i;
        float vals[8];
        #pragma unroll
        for (int j = 0; j < 8; ++j) {
            float v = acc[i][j];
            if (BIAS) {
                const int bi = j0 + tx * 8 + j;
                v += fmt ? ((const float*)bias)[bi] : b2f(((const u16*)bias)[bi]);
            }
            if (RELU) v = fmaxf(v, 0.f) + 1e-6f;
            vals[j] = v;
        }
        if (CEXT && fmt) {
            float* cp = (float*)Cout + (size_t)m * ldc + j0 + tx * 8;
            *(float4*)cp       = make_float4(vals[0], vals[1], vals[2], vals[3]);
            *(float4*)(cp + 4) = make_float4(vals[4], vals[5], vals[6], vals[7]);
        } else {
            union { uint4 v; u16 s[8]; } o;
            #pragma unroll
            for (int j = 0; j < 8; ++j) o.s[j] = f2b(vals[j]);
            *(uint4*)((u16*)Cout + (size_t)m * ldc + j0 + tx * 8) = o.v;
        }
    }
}

// k_mean[b, c] = mean_n k[b, n, c]
__global__ __launch_bounds__(256)
void kmean_kernel(const u16* __restrict__ k, float* __restrict__ km)
{
    const int c  = blockIdx.x * 256 + threadIdx.x;
    const int b  = blockIdx.y;
    const int nc = blockIdx.z;
    const u16* p = k + ((size_t)b * N_ + nc * 256) * C_ + c;
    float s = 0.f;
    for (int n = 0; n < 256; ++n) s += b2f(p[(size_t)n * C_]);
    atomicAdd(&km[b * C_ + c], s * (1.0f / N_));
}

// kvh[bh, d*64+e] += (1/N) * sum_{n in chunk} k*v
__global__ __launch_bounds__(256)
void kv_atomic(const u16* __restrict__ k, const u16* __restrict__ v,
               float* __restrict__ kvh)
{
    __shared__ float kk[4][64];
    __shared__ float vv[4][64];
    const int bh = blockIdx.x;
    const int ch = blockIdx.y;
    const int b = bh >> 4, h = bh & 15;
    const int t = threadIdx.x;
    const int e = t & 63, d0 = (t >> 6) * 16;
    const int lr = t >> 6, lc = t & 63;
    const int n0 = ch * 512;
    float acc[16];
    #pragma unroll
    for (int i = 0; i < 16; ++i) acc[i] = 0.f;

    for (int nb = 0; nb < 512; nb += 4) {
        size_t base = ((size_t)(b * N_ + n0 + nb + lr)) * C_ + h * 64 + lc;
        float kf = b2f(k[base]);
        float vf = b2f(v[base]);
        __syncthreads();
        kk[lr][lc] = kf;
        vv[lr][lc] = vf;
        __syncthreads();
        #pragma unroll
        for (int r = 0; r < 4; ++r) {
            float ve = vv[r][e];
            #pragma unroll
            for (int i = 0; i < 16; ++i) acc[i] += kk[r][d0 + i] * ve;
        }
    }
    float* dst = kvh + (size_t)bh * 4096;
    #pragma unroll
    for (int i = 0; i < 16; ++i)
        atomicAdd(&dst[(d0 + i) * 64 + e], acc[i] * (1.0f / N_));
}

// ---------------------------------------------------------------------------
// att: y = (q @ KV_h) * z.   kv column e held in 64 VGPRs (reused over all
// 16 rows) -> inner loop is wave-uniform ds_read_b128 of qs + VALU FMA.
// ---------------------------------------------------------------------------
__global__ __launch_bounds__(256)
void att_kernel(const u16* __restrict__ q, const float* __restrict__ kvh,
                const float* __restrict__ kmean, u16* __restrict__ y)
{
    __shared__ float kvs[64 * 64];
    __shared__ float qs[64 * 68];     // 68-float pitch: 272 B, 16B-aligned rows
    __shared__ float kmv[64];
    __shared__ float zs[64];
    const int bh = blockIdx.y;
    const int b = bh >> 4, h = bh & 15;
    const int n0 = blockIdx.x * 64;
    const int t = threadIdx.x;
    const int e = t & 63, rg = t >> 6;

    // cooperative loads (vectorized)
    const float4* kvsrc4 = (const float4*)(kvh + (size_t)bh * 4096);
    #pragma unroll
    for (int i = 0; i < 4; ++i)
        *(float4*)&kvs[(i * 256 + t) * 4] = kvsrc4[i * 256 + t];
    if (t < 64) kmv[t] = kmean[b * C_ + h * 64 + t];
    #pragma unroll
    for (int ii = 0; ii < 2; ++ii) {
        int i = ii * 256 + t;               // 512 x uint4 = 4096 u16
        int r = i >> 3, c8 = (i & 7) * 8;
        uint4 v = *(const uint4*)&q[((size_t)(b * N_ + n0 + r)) * C_ + h * 64 + c8];
        float f[8];
        unpack8(v, f);
        #pragma unroll
        for (int j = 0; j < 8; ++j) qs[r * 68 + c8 + j] = f[j];
    }
    __syncthreads();

    // kv column e -> registers (stride-1 across lanes: conflict-free)
    float kvr[64];
    #pragma unroll
    for (int d = 0; d < 64; ++d) kvr[d] = kvs[d * 64 + e];

    if (t < 64) {
        float s = 1e-6f;
        #pragma unroll
        for (int d = 0; d < 64; ++d) s += qs[t * 68 + d] * kmv[d];
        zs[t] = 1.0f / s;
    }
    __syncthreads();

    for (int rr = 0; rr < 16; ++rr) {
        int r = rg * 16 + rr;
        float acc = 0.f;
        #pragma unroll
        for (int d = 0; d < 64; ++d) acc += qs[r * 68 + d] * kvr[d];
        y[((size_t)(b * N_ + n0 + r)) * C_ + h * 64 + e] = f2b(acc * zs[r]);
    }
}

// ---------------------------------------------------------------------------
// Depthwise 5x5 conv over v, add into y — channel-vectorized (uint4 = 8 bf16).
// ---------------------------------------------------------------------------
__global__ __launch_bounds__(256)
void conv_add(const u16* __restrict__ v, const void* __restrict__ w,
              const void* __restrict__ wb, u16* __restrict__ y,
              const int* __restrict__ flag)
{
    __shared__ float wt[25][64];
    __shared__ float bl[64];
    const int fmt = flag[0];
    const int t = threadIdx.x;
    for (int i = t; i < 1600; i += 256) {
        const int tap = i >> 6, c = i & 63;
        const int src = c * 25 + tap;
        wt[tap][c] = fmt ? ((const float*)w)[src] : b2f(((const u16*)w)[src]);
    }
    if (t < 64)
        bl[t] = fmt ? ((const float*)wb)[t] : b2f(((const u16*)wb)[t]);
    __syncthreads();

    const size_t gid = (size_t)blockIdx.x * 256 + t;   // 0 .. 2,097,151
    const int cg = (int)(gid & 127);                   // channel-group (8 ch)
    const int n  = (int)((gid >> 7) & 4095);           // pixel (wave-uniform)
    const int b  = (int)(gid >> 19);
    const int c0 = cg * 8;
    const int cb = c0 & 63;                            // weight channel base
    const int yp = n >> 6, xp = n & 63;

    float acc[8];
    #pragma unroll
    for (int j = 0; j < 8; ++j) acc[j] = bl[cb + j];

    const u16* vbase = v + (size_t)b * N_ * C_ + c0;
    #pragma unroll
    for (int dy = 0; dy < 5; ++dy) {
        const int yy = yp + dy - 2;
        if (yy < 0 || yy >= HW_) continue;
        #pragma unroll
        for (int dx = 0; dx < 5; ++dx) {
            const int xx = xp + dx - 2;
            if (xx < 0 || xx >= HW_) continue;
            uint4 pv = *(const uint4*)(vbase + (size_t)(yy * HW_ + xx) * C_);
            float f[8];
            unpack8(pv, f);
            const int tap = dy * 5 + dx;
            float4 w0 = *(const float4*)&wt[tap][cb];
            float4 w1 = *(const float4*)&wt[tap][cb + 4];
            acc[0] += w0.x * f[0]; acc[1] += w0.y * f[1];
            acc[2] += w0.z * f[2]; acc[3] += w0.w * f[3];
            acc[4] += w1.x * f[4]; acc[5] += w1.y * f[5];
            acc[6] += w1.z * f[6]; acc[7] += w1.w * f[7];
        }
    }

    uint4 yv = *(const uint4*)(y + gid * 8);
    float yf[8];
    unpack8(yv, yf);
    union { uint4 v4; u16 s[8]; } o;
    #pragma unroll
    for (int j = 0; j < 8; ++j) o.s[j] = f2b(yf[j] + acc[j]);
    *(uint4*)(y + gid * 8) = o.v4;
}

extern "C" void kernel_launch(void* const* d_in, const int* in_sizes, int n_in,
                              void* d_out, int out_size, void* d_ws, size_t ws_size,
                              hipStream_t stream)
{
    const void* x     = d_in[0];
    const void* Wq    = d_in[1];
    const void* Wkv   = d_in[2];
    const void* Wproj = d_in[3];
    const void* bproj = d_in[4];
    const void* dwc_w = d_in[5];
    const void* dwc_b = d_in[6];

    char* ws = (char*)d_ws;
    const size_t MI = 1024 * 1024;
    const size_t NEED_FAST = 35 * MI + 17 * 1024;
    const size_t OUT_F32   = (size_t)NT_ * C_ * sizeof(float);   // 64 MB

    if (ws_size >= NEED_FAST && (size_t)out_size >= OUT_F32) {
        // ---- fastest path: x pre-converted to bf16 -> all GEMMs use the
        //      ring-4 pipelined path (AEXT=0). ----
        u16*   vbuf  = (u16*)ws;
        u16*   WT    = (u16*)(ws + 32 * MI);
        float* kvh   = (float*)(ws + 34 * MI);
        float* kmean = (float*)(ws + 35 * MI);
        int*   flag  = (int*)(ws + 35 * MI + 16 * 1024);
        u16*   xb    = (u16*)d_out;                       // lower 32 MB of out
        u16*   kq    = (u16*)d_out + (size_t)NT_ * C_;    // upper 32 MB of out
        u16*   ybuf  = (u16*)ws;

        detect_fmt<<<1, 256, 0, stream>>>((const u16*)x, flag);
        zero_f32<<<dim3(1040), 256, 0, stream>>>(kvh, 266240);   // kvh + kmean contiguous
        convert_x<<<dim3(2048), 256, 0, stream>>>(x, xb, flag);

        // v = xb @ Wkv[:, C:]
        transpose_w<<<dim3(16, 16), 256, 0, stream>>>(Wkv, WT, flag, 2 * C_, C_, C_);
        gemm_mfma<0, 0, 0, 0><<<dim3(8, 128), 256, 0, stream>>>(xb, WT, vbuf, nullptr, flag, C_, C_);
        // k = relu(xb @ Wkv[:, :C]) + eps
        transpose_w<<<dim3(16, 16), 256, 0, stream>>>(Wkv, WT, flag, 2 * C_, 0, C_);
        gemm_mfma<1, 0, 0, 0><<<dim3(8, 128), 256, 0, stream>>>(xb, WT, kq, nullptr, flag, C_, C_);

        kmean_kernel<<<dim3(4, B_, 16), 256, 0, stream>>>(kq, kmean);
        kv_atomic<<<dim3(64, 8), 256, 0, stream>>>(kq, vbuf, kvh);

        // q = relu(xb @ Wq) + eps  (overwrites k; k dead, xb disjoint)
        transpose_w<<<dim3(16, 16), 256, 0, stream>>>(Wq, WT, flag, C_, 0, C_);
        gemm_mfma<1, 0, 0, 0><<<dim3(8, 128), 256, 0, stream>>>(xb, WT, kq, nullptr, flag, C_, C_);

        att_kernel<<<dim3(64, 64), 256, 0, stream>>>(kq, kvh, kmean, kq);
        conv_add<<<dim3(8192), 256, 0, stream>>>(vbuf, dwc_w, dwc_b, kq, flag);

        // move y into ws (v dead), then out = y @ Wproj + bproj (fp32 over all of d_out)
        hipMemcpyAsync(ws, kq, (size_t)NT_ * C_ * sizeof(u16), hipMemcpyDeviceToDevice, stream);
        transpose_w<<<dim3(16, 16), 256, 0, stream>>>(Wproj, WT, flag, C_, 0, C_);
        gemm_mfma<0, 1, 0, 1><<<dim3(8, 128), 256, 0, stream>>>(ybuf, WT, d_out, bproj, flag, C_, C_);
    } else if (ws_size >= NEED_FAST) {
        // ---- previous fast path (MFMA, fp32 A staged in-loop; AEXT=1 legacy) ----
        u16*   vbuf  = (u16*)ws;
        u16*   WT    = (u16*)(ws + 32 * MI);
        float* kvh   = (float*)(ws + 34 * MI);
        float* kmean = (float*)(ws + 35 * MI);
        int*   flag  = (int*)(ws + 35 * MI + 16 * 1024);
        u16*   kq    = (u16*)d_out;
        u16*   ybuf  = (u16*)ws;

        detect_fmt<<<1, 256, 0, stream>>>((const u16*)x, flag);
        zero_f32<<<dim3(1040), 256, 0, stream>>>(kvh, 266240);

        transpose_w<<<dim3(16, 16), 256, 0, stream>>>(Wkv, WT, flag, 2 * C_, C_, C_);
        gemm_mfma<0, 0, 1, 0><<<dim3(8, 128), 256, 0, stream>>>(x, WT, vbuf, nullptr, flag, C_, C_);
        transpose_w<<<dim3(16, 16), 256, 0, stream>>>(Wkv, WT, flag, 2 * C_, 0, C_);
        gemm_mfma<1, 0, 1, 0><<<dim3(8, 128), 256, 0, stream>>>(x, WT, kq, nullptr, flag, C_, C_);

        kmean_kernel<<<dim3(4, B_, 16), 256, 0, stream>>>(kq, kmean);
        kv_atomic<<<dim3(64, 8), 256, 0, stream>>>(kq, vbuf, kvh);

        transpose_w<<<dim3(16, 16), 256, 0, stream>>>(Wq, WT, flag, C_, 0, C_);
        gemm_mfma<1, 0, 1, 0><<<dim3(8, 128), 256, 0, stream>>>(x, WT, kq, nullptr, flag, C_, C_);

        att_kernel<<<dim3(64, 64), 256, 0, stream>>>(kq, kvh, kmean, kq);
        conv_add<<<dim3(8192), 256, 0, stream>>>(vbuf, dwc_w, dwc_b, kq, flag);

        hipMemcpyAsync(ws, d_out, (size_t)NT_ * C_ * sizeof(u16), hipMemcpyDeviceToDevice, stream);
        transpose_w<<<dim3(16, 16), 256, 0, stream>>>(Wproj, WT, flag, C_, 0, C_);
        gemm_mfma<0, 1, 0, 1><<<dim3(8, 128), 256, 0, stream>>>(ybuf, WT, d_out, bproj, flag, C_, C_);
    } else {
        // ---- fallback path (proven) ----
        u16*   vbuf  = (u16*)ws;
        float* kmean = (float*)(ws + 32 * MI);
        float* kvh   = (float*)(ws + 32 * MI + 16 * 1024);
        int*   flag  = (int*)(ws + 32 * MI + 16 * 1024 + 1 * MI);
        u16*   kq    = (u16*)d_out;
        u16*   ybuf  = (u16*)ws;

        detect_fmt<<<1, 256, 0, stream>>>((const u16*)x, flag);
        zero_f32<<<dim3(1040), 256, 0, stream>>>(kmean, 266240);

        gemm_any<0, 0, 1, 0><<<dim3(8, 128), 256, 0, stream>>>(x, Wkv, vbuf, nullptr, flag, NT_, C_, 2 * C_, C_, C_);
        gemm_any<1, 0, 1, 0><<<dim3(8, 128), 256, 0, stream>>>(x, Wkv, kq,   nullptr, flag, NT_, C_, 2 * C_, 0,  C_);

        kmean_kernel<<<dim3(4, B_, 16), 256, 0, stream>>>(kq, kmean);
        kv_atomic<<<dim3(64, 8), 256, 0, stream>>>(kq, vbuf, kvh);

        gemm_any<1, 0, 1, 0><<<dim3(8, 128), 256, 0, stream>>>(x, Wq, kq, nullptr, flag, NT_, C_, C_, 0, C_);

        att_kernel<<<dim3(64, 64), 256, 0, stream>>>(kq, kvh, kmean, kq);
        conv_add<<<dim3(8192), 256, 0, stream>>>(vbuf, dwc_w, dwc_b, kq, flag);

        hipMemcpyAsync(ws, d_out, (size_t)NT_ * C_ * sizeof(u16), hipMemcpyDeviceToDevice, stream);
        gemm_any<0, 1, 0, 1><<<dim3(8, 128), 256, 0, stream>>>(ybuf, Wproj, d_out, bproj, flag, NT_, C_, C_, 0, C_);
    }
}

// Round 9
// 574.066 us; speedup vs baseline: 1.1676x; 1.1518x over previous
//
#include <hip/hip_runtime.h>
#include <stdint.h>

typedef unsigned short u16;   // bf16 bits

#define B_   4
#define N_   4096
#define C_   1024
#define NT_  (B_*N_)          // 16384 rows
#define HW_  64               // H = W = 64

typedef __attribute__((ext_vector_type(8))) short bf16x8;
typedef __attribute__((ext_vector_type(4))) float f32x4;

__device__ __forceinline__ float b2f(u16 s) {
    union { uint32_t u; float f; } x; x.u = ((uint32_t)s) << 16; return x.f;
}
__device__ __forceinline__ u16 f2b(float f) {
    union { float f; uint32_t u; } x; x.f = f;
    uint32_t u = x.u;
    return (u16)((u + 0x7FFFu + ((u >> 16) & 1u)) >> 16);   // RNE
}
__device__ __forceinline__ float lo2f(uint32_t u) {
    union { uint32_t u; float f; } x; x.u = u << 16; return x.f;
}
__device__ __forceinline__ float hi2f(uint32_t u) {
    union { uint32_t u; float f; } x; x.u = u & 0xFFFF0000u; return x.f;
}
__device__ __forceinline__ void unpack8(uint4 v, float* f) {
    f[0] = lo2f(v.x); f[1] = hi2f(v.x); f[2] = lo2f(v.y); f[3] = hi2f(v.y);
    f[4] = lo2f(v.z); f[5] = hi2f(v.z); f[6] = lo2f(v.w); f[7] = hi2f(v.w);
}

// ---------------------------------------------------------------------------
// Input format detector (0 = bf16, 1 = fp32).
// ---------------------------------------------------------------------------
__global__ void detect_fmt(const u16* __restrict__ x, int* __restrict__ flag)
{
    __shared__ int smax[256];
    const int t = threadIdx.x;
    int m = 0;
    for (int i = t; i < 2048; i += 256) {
        int e = (x[2 * i] >> 7) & 0xFF;
        m = m > e ? m : e;
    }
    smax[t] = m;
    __syncthreads();
    for (int s = 128; s > 0; s >>= 1) {
        if (t < s) smax[t] = smax[t] > smax[t + s] ? smax[t] : smax[t + s];
        __syncthreads();
    }
    if (t == 0) flag[0] = (smax[0] >= 0x90) ? 1 : 0;
}

__global__ void zero_f32(float* p, int n) {
    int i = blockIdx.x * 256 + threadIdx.x;
    if (i < n) p[i] = 0.f;
}

// ---------------------------------------------------------------------------
// x (fp32 or bf16 per flag) -> bf16, one streaming pass.
// ---------------------------------------------------------------------------
__global__ __launch_bounds__(256)
void convert_x(const void* __restrict__ x, u16* __restrict__ xb,
               const int* __restrict__ flag)
{
    const int fmt = flag[0];
    const size_t total = (size_t)NT_ * C_ / 8;          // 2,097,152 vec8
    const size_t stride = (size_t)gridDim.x * 256;
    size_t i = (size_t)blockIdx.x * 256 + threadIdx.x;
    if (fmt) {
        for (; i < total; i += stride) {
            const float4* p = (const float4*)x + i * 2;
            float4 a = p[0], b = p[1];
            union { uint4 v; u16 s[8]; } o;
            o.s[0] = f2b(a.x); o.s[1] = f2b(a.y); o.s[2] = f2b(a.z); o.s[3] = f2b(a.w);
            o.s[4] = f2b(b.x); o.s[5] = f2b(b.y); o.s[6] = f2b(b.z); o.s[7] = f2b(b.w);
            ((uint4*)xb)[i] = o.v;
        }
    } else {
        for (; i < total; i += stride)
            ((uint4*)xb)[i] = ((const uint4*)x)[i];
    }
}

// ---------------------------------------------------------------------------
// Weight transpose: WT[n, k] = W[k, col0+n] as bf16. W fmt per flag.
// ---------------------------------------------------------------------------
__global__ __launch_bounds__(256)
void transpose_w(const void* __restrict__ W, u16* __restrict__ WT,
                 const int* __restrict__ flag, int ldw, int col0, int Kdim)
{
    __shared__ u16 tile[64][65];
    const int fmt = flag[0];
    const int n0 = blockIdx.x * 64, k0 = blockIdx.y * 64;
    const int t = threadIdx.x;
    const int c = t & 63, rg = t >> 6;
    #pragma unroll 4
    for (int i = 0; i < 16; ++i) {
        int r = rg * 16 + i;
        size_t gi = (size_t)(k0 + r) * ldw + col0 + n0 + c;
        tile[r][c] = fmt ? f2b(((const float*)W)[gi]) : ((const u16*)W)[gi];
    }
    __syncthreads();
    #pragma unroll 4
    for (int i = 0; i < 16; ++i) {
        int r = rg * 16 + i;
        WT[(size_t)(n0 + r) * Kdim + k0 + c] = tile[c][r];
    }
}

// ---------------------------------------------------------------------------
// MFMA GEMM: C[m, j] = sum_k A[m,k] * BT[j,k]   (BT: n-major bf16)
// 128x128 tile, 4 waves (2x2), 4x4 x mfma_f32_16x16x32_bf16 per wave.
//
// AEXT==0: ring-4 pipeline, 3 tiles in flight, counted vmcnt(12).
//   All buffer indices are compile-time literals; barriers are
//   asm volatile("s_barrier":::"memory") bracketed by sched_barrier(0);
//   setprio(1) around MFMA cluster. Correctness HW-validated in R5-R7
//   (every branch's final Wproj GEMM runs this path; output passed).
//   REQUIRES: K multiple of 128 (all call sites use K=1024).
// AEXT==1: legacy single-buffer 2-barrier structure (fp32 A support).
// ---------------------------------------------------------------------------
template<int RELU, int BIAS, int AEXT, int CEXT>
__global__ __launch_bounds__(256)
void gemm_mfma(const void* __restrict__ A, const u16* __restrict__ BT,
               void* __restrict__ Cout, const void* __restrict__ bias,
               const int* __restrict__ flag, int K, int ldc)
{
    __shared__ u16 As[AEXT ? 1 : 4][128 * 32];
    __shared__ u16 Bs[AEXT ? 1 : 4][128 * 32];
    const int fmt = flag[0];
    const int t    = threadIdx.x;
    const int lane = t & 63;
    const int w    = t >> 6;          // wave 0..3
    const int wm   = w >> 1, wn = w & 1;
    const int quad = lane >> 4;       // 0..3
    const int l16  = lane & 15;

    int bid = blockIdx.y * gridDim.x + blockIdx.x;
    const int nwg = gridDim.x * gridDim.y;
    if ((nwg & 7) == 0)
        bid = (bid & 7) * (nwg >> 3) + (bid >> 3);   // bijective chunked swizzle
    const int j0 = (bid % gridDim.x) * 128;
    const int m0 = (bid / gridDim.x) * 128;

    const int srow = lane >> 2;
    const int gseg = ((lane & 3) ^ ((lane >> 3) & 3)) * 8;

    f32x4 acc[4][4] = {};

    if (AEXT) {
        // -------- legacy path (handles fp32 A; single buffer, __syncthreads) --------
        for (int k0 = 0; k0 < K; k0 += 32) {
            if (fmt) {
                #pragma unroll
                for (int i = 0; i < 2; ++i) {
                    const int r0 = w * 32 + i * 16;
                    const float* gp = (const float*)A + (size_t)(m0 + r0 + srow) * K + k0 + gseg;
                    float4 f0 = *(const float4*)gp;
                    float4 f1 = *(const float4*)(gp + 4);
                    union { bf16x8 v; u16 s[8]; } o;
                    o.s[0] = f2b(f0.x); o.s[1] = f2b(f0.y); o.s[2] = f2b(f0.z); o.s[3] = f2b(f0.w);
                    o.s[4] = f2b(f1.x); o.s[5] = f2b(f1.y); o.s[6] = f2b(f1.z); o.s[7] = f2b(f1.w);
                    *(bf16x8*)&As[0][(r0 + srow) * 32 + (lane & 3) * 8] = o.v;
                }
            } else {
                #pragma unroll
                for (int i = 0; i < 2; ++i) {
                    const int r0 = w * 32 + i * 16;
                    const u16* gp = (const u16*)A + (size_t)(m0 + r0 + srow) * K + k0 + gseg;
                    __builtin_amdgcn_global_load_lds(
                        (const __attribute__((address_space(1))) void*)gp,
                        (__attribute__((address_space(3))) void*)&As[0][r0 * 32], 16, 0, 0);
                }
            }
            #pragma unroll
            for (int i = 0; i < 2; ++i) {
                const int r0 = w * 32 + i * 16;
                const u16* gp = BT + (size_t)(j0 + r0 + srow) * K + k0 + gseg;
                __builtin_amdgcn_global_load_lds(
                    (const __attribute__((address_space(1))) void*)gp,
                    (__attribute__((address_space(3))) void*)&Bs[0][r0 * 32], 16, 0, 0);
            }
            __syncthreads();

            bf16x8 af[4], bfr[4];
            #pragma unroll
            for (int mt = 0; mt < 4; ++mt) {
                const int r = wm * 64 + mt * 16 + l16;
                const int slot = quad ^ ((r >> 1) & 3);
                af[mt] = *(const bf16x8*)&As[0][r * 32 + slot * 8];
            }
            #pragma unroll
            for (int nt = 0; nt < 4; ++nt) {
                const int r = wn * 64 + nt * 16 + l16;
                const int slot = quad ^ ((r >> 1) & 3);
                bfr[nt] = *(const bf16x8*)&Bs[0][r * 32 + slot * 8];
            }
            #pragma unroll
            for (int mt = 0; mt < 4; ++mt)
                #pragma unroll
                for (int nt = 0; nt < 4; ++nt)
                    acc[mt][nt] = __builtin_amdgcn_mfma_f32_16x16x32_bf16(
                        af[mt], bfr[nt], acc[mt][nt], 0, 0, 0);
            __syncthreads();
        }
    } else {
        // -------- ring-4 counted-vmcnt pipeline (A, B both bf16) --------
        auto stage = [&](int buf, int tile) {
            const int kk = tile * 32;
            #pragma unroll
            for (int i = 0; i < 2; ++i) {
                const int r0 = w * 32 + i * 16;
                const u16* gp = (const u16*)A + (size_t)(m0 + r0 + srow) * K + kk + gseg;
                __builtin_amdgcn_global_load_lds(
                    (const __attribute__((address_space(1))) void*)gp,
                    (__attribute__((address_space(3))) void*)&As[buf][r0 * 32], 16, 0, 0);
            }
            #pragma unroll
            for (int i = 0; i < 2; ++i) {
                const int r0 = w * 32 + i * 16;
                const u16* gp = BT + (size_t)(j0 + r0 + srow) * K + kk + gseg;
                __builtin_amdgcn_global_load_lds(
                    (const __attribute__((address_space(1))) void*)gp,
                    (__attribute__((address_space(3))) void*)&Bs[buf][r0 * 32], 16, 0, 0);
            }
        };
        auto compute = [&](int buf) {
            bf16x8 af[4], bfr[4];
            #pragma unroll
            for (int mt = 0; mt < 4; ++mt) {
                const int r = wm * 64 + mt * 16 + l16;
                const int slot = quad ^ ((r >> 1) & 3);
                af[mt] = *(const bf16x8*)&As[buf][r * 32 + slot * 8];
            }
            #pragma unroll
            for (int nt = 0; nt < 4; ++nt) {
                const int r = wn * 64 + nt * 16 + l16;
                const int slot = quad ^ ((r >> 1) & 3);
                bfr[nt] = *(const bf16x8*)&Bs[buf][r * 32 + slot * 8];
            }
            __builtin_amdgcn_s_setprio(1);
            #pragma unroll
            for (int mt = 0; mt < 4; ++mt)
                #pragma unroll
                for (int nt = 0; nt < 4; ++nt)
                    acc[mt][nt] = __builtin_amdgcn_mfma_f32_16x16x32_bf16(
                        af[mt], bfr[nt], acc[mt][nt], 0, 0, 0);
            __builtin_amdgcn_s_setprio(0);
        };
        #define GBAR() do {                                   \
            __builtin_amdgcn_sched_barrier(0);                \
            asm volatile("s_barrier" ::: "memory");           \
            __builtin_amdgcn_sched_barrier(0);                \
        } while (0)

        const int nsteps = K >> 5;        // 32-wide K tiles; nsteps % 4 == 0
        // prologue: 3 tiles in flight (12 loads/wave)
        stage(0, 0); stage(1, 1); stage(2, 2);

        int tt = 0;
        for (; tt + 4 < nsteps; tt += 4) {
            stage(3, tt + 3);
            asm volatile("s_waitcnt vmcnt(12)" ::: "memory");
            GBAR(); compute(0); GBAR();
            stage(0, tt + 4);
            asm volatile("s_waitcnt vmcnt(12)" ::: "memory");
            GBAR(); compute(1); GBAR();
            stage(1, tt + 5);
            asm volatile("s_waitcnt vmcnt(12)" ::: "memory");
            GBAR(); compute(2); GBAR();
            stage(2, tt + 6);
            asm volatile("s_waitcnt vmcnt(12)" ::: "memory");
            GBAR(); compute(3); GBAR();
        }
        // tail: tt == nsteps-4; stage last tile, then drain 12 -> 8 -> 4 -> 0
        stage(3, tt + 3);
        asm volatile("s_waitcnt vmcnt(12)" ::: "memory");
        GBAR(); compute(0); GBAR();
        asm volatile("s_waitcnt vmcnt(8)" ::: "memory");
        GBAR(); compute(1); GBAR();
        asm volatile("s_waitcnt vmcnt(4)" ::: "memory");
        GBAR(); compute(2); GBAR();
        asm volatile("s_waitcnt vmcnt(0)" ::: "memory");
        GBAR(); compute(3);
        #undef GBAR
    }

    #pragma unroll
    for (int mt = 0; mt < 4; ++mt) {
        #pragma unroll
        for (int nt = 0; nt < 4; ++nt) {
            const int col = j0 + wn * 64 + nt * 16 + l16;
            float bv = 0.f;
            if (BIAS) bv = fmt ? ((const float*)bias)[col] : b2f(((const u16*)bias)[col]);
            #pragma unroll
            for (int r = 0; r < 4; ++r) {
                const int row = m0 + wm * 64 + mt * 16 + quad * 4 + r;
                float v = acc[mt][nt][r];
                if (BIAS) v += bv;
                if (RELU) v = fmaxf(v, 0.f) + 1e-6f;
                if (CEXT && fmt) ((float*)Cout)[(size_t)row * ldc + col] = v;
                else             ((u16*)Cout)[(size_t)row * ldc + col] = f2b(v);
            }
        }
    }
}

// ---------------------------------------------------------------------------
// Fallback VALU GEMM (proven) — used only if ws_size is too small.
// ---------------------------------------------------------------------------
template<int RELU, int BIAS, int AEXT, int CEXT>
__global__ __launch_bounds__(256)
void gemm_any(const void* __restrict__ A, const void* __restrict__ Bm,
              void* __restrict__ Cout, const void* __restrict__ bias,
              const int* __restrict__ flag,
              int M, int K, int ldb, int bcol0, int ldc)
{
    const int fmt = flag[0];
    __shared__ float As[16][128];
    __shared__ float Bs[16][128];
    const int t  = threadIdx.x;
    const int tx = t & 15, ty = t >> 4;
    const int m0 = blockIdx.y * 128;
    const int j0 = blockIdx.x * 128;
    const int la_row = t >> 1;
    const int la_k   = (t & 1) * 8;
    const int lb_k   = t >> 4;
    const int lb_j   = (t & 15) * 8;

    float acc[8][8];
    #pragma unroll
    for (int i = 0; i < 8; ++i)
        #pragma unroll
        for (int j = 0; j < 8; ++j) acc[i][j] = 0.f;

    for (int k0 = 0; k0 < K; k0 += 16) {
        float af[8], bfv[8];
        if (AEXT && fmt) {
            const float* ap = (const float*)A + (size_t)(m0 + la_row) * K + k0 + la_k;
            float4 a0 = *(const float4*)ap;
            float4 a1 = *(const float4*)(ap + 4);
            af[0] = a0.x; af[1] = a0.y; af[2] = a0.z; af[3] = a0.w;
            af[4] = a1.x; af[5] = a1.y; af[6] = a1.z; af[7] = a1.w;
        } else {
            uint4 av = *(const uint4*)((const u16*)A + (size_t)(m0 + la_row) * K + k0 + la_k);
            unpack8(av, af);
        }
        if (fmt) {
            const float* bp = (const float*)Bm + (size_t)(k0 + lb_k) * ldb + bcol0 + j0 + lb_j;
            float4 b0 = *(const float4*)bp;
            float4 b1 = *(const float4*)(bp + 4);
            bfv[0] = b0.x; bfv[1] = b0.y; bfv[2] = b0.z; bfv[3] = b0.w;
            bfv[4] = b1.x; bfv[5] = b1.y; bfv[6] = b1.z; bfv[7] = b1.w;
        } else {
            uint4 bv = *(const uint4*)((const u16*)Bm + (size_t)(k0 + lb_k) * ldb + bcol0 + j0 + lb_j);
            unpack8(bv, bfv);
        }
        __syncthreads();
        #pragma unroll
        for (int i = 0; i < 8; ++i) As[la_k + i][la_row] = af[i];
        *(float4*)&Bs[lb_k][lb_j]     = make_float4(bfv[0], bfv[1], bfv[2], bfv[3]);
        *(float4*)&Bs[lb_k][lb_j + 4] = make_float4(bfv[4], bfv[5], bfv[6], bfv[7]);
        __syncthreads();
        #pragma unroll
        for (int kk = 0; kk < 16; ++kk) {
            float a[8], b[8];
            *(float4*)&a[0] = *(const float4*)&As[kk][ty * 8];
            *(float4*)&a[4] = *(const float4*)&As[kk][ty * 8 + 4];
            *(float4*)&b[0] = *(const float4*)&Bs[kk][tx * 8];
            *(float4*)&b[4] = *(const float4*)&Bs[kk][tx * 8 + 4];
            #pragma unroll
            for (int i = 0; i < 8; ++i)
                #pragma unroll
                for (int j = 0; j < 8; ++j)
                    acc[i][j] += a[i] * b[j];
        }
    }

    #pragma unroll
    for (int i = 0; i < 8; ++i) {
        const int m = m0 + ty * 8 + i;
        float vals[8];
        #pragma unroll
        for (int j = 0; j < 8; ++j) {
            float v = acc[i][j];
            if (BIAS) {
                const int bi = j0 + tx * 8 + j;
                v += fmt ? ((const float*)bias)[bi] : b2f(((const u16*)bias)[bi]);
            }
            if (RELU) v = fmaxf(v, 0.f) + 1e-6f;
            vals[j] = v;
        }
        if (CEXT && fmt) {
            float* cp = (float*)Cout + (size_t)m * ldc + j0 + tx * 8;
            *(float4*)cp       = make_float4(vals[0], vals[1], vals[2], vals[3]);
            *(float4*)(cp + 4) = make_float4(vals[4], vals[5], vals[6], vals[7]);
        } else {
            union { uint4 v; u16 s[8]; } o;
            #pragma unroll
            for (int j = 0; j < 8; ++j) o.s[j] = f2b(vals[j]);
            *(uint4*)((u16*)Cout + (size_t)m * ldc + j0 + tx * 8) = o.v;
        }
    }
}

// k_mean[b, c] = mean_n k[b, n, c]
__global__ __launch_bounds__(256)
void kmean_kernel(const u16* __restrict__ k, float* __restrict__ km)
{
    const int c  = blockIdx.x * 256 + threadIdx.x;
    const int b  = blockIdx.y;
    const int nc = blockIdx.z;
    const u16* p = k + ((size_t)b * N_ + nc * 256) * C_ + c;
    float s = 0.f;
    for (int n = 0; n < 256; ++n) s += b2f(p[(size_t)n * C_]);
    atomicAdd(&km[b * C_ + c], s * (1.0f / N_));
}

// kvh[bh, d*64+e] += (1/N) * sum_{n in chunk} k*v
__global__ __launch_bounds__(256)
void kv_atomic(const u16* __restrict__ k, const u16* __restrict__ v,
               float* __restrict__ kvh)
{
    __shared__ float kk[4][64];
    __shared__ float vv[4][64];
    const int bh = blockIdx.x;
    const int ch = blockIdx.y;
    const int b = bh >> 4, h = bh & 15;
    const int t = threadIdx.x;
    const int e = t & 63, d0 = (t >> 6) * 16;
    const int lr = t >> 6, lc = t & 63;
    const int n0 = ch * 512;
    float acc[16];
    #pragma unroll
    for (int i = 0; i < 16; ++i) acc[i] = 0.f;

    for (int nb = 0; nb < 512; nb += 4) {
        size_t base = ((size_t)(b * N_ + n0 + nb + lr)) * C_ + h * 64 + lc;
        float kf = b2f(k[base]);
        float vf = b2f(v[base]);
        __syncthreads();
        kk[lr][lc] = kf;
        vv[lr][lc] = vf;
        __syncthreads();
        #pragma unroll
        for (int r = 0; r < 4; ++r) {
            float ve = vv[r][e];
            #pragma unroll
            for (int i = 0; i < 16; ++i) acc[i] += kk[r][d0 + i] * ve;
        }
    }
    float* dst = kvh + (size_t)bh * 4096;
    #pragma unroll
    for (int i = 0; i < 16; ++i)
        atomicAdd(&dst[(d0 + i) * 64 + e], acc[i] * (1.0f / N_));
}

// ---------------------------------------------------------------------------
// att: y = (q @ KV_h) * z.   kv column e held in 64 VGPRs (reused over all
// 16 rows) -> inner loop is wave-uniform ds_read_b128 of qs + VALU FMA.
// ---------------------------------------------------------------------------
__global__ __launch_bounds__(256)
void att_kernel(const u16* __restrict__ q, const float* __restrict__ kvh,
                const float* __restrict__ kmean, u16* __restrict__ y)
{
    __shared__ float kvs[64 * 64];
    __shared__ float qs[64 * 68];     // 68-float pitch: 272 B, 16B-aligned rows
    __shared__ float kmv[64];
    __shared__ float zs[64];
    const int bh = blockIdx.y;
    const int b = bh >> 4, h = bh & 15;
    const int n0 = blockIdx.x * 64;
    const int t = threadIdx.x;
    const int e = t & 63, rg = t >> 6;

    // cooperative loads (vectorized)
    const float4* kvsrc4 = (const float4*)(kvh + (size_t)bh * 4096);
    #pragma unroll
    for (int i = 0; i < 4; ++i)
        *(float4*)&kvs[(i * 256 + t) * 4] = kvsrc4[i * 256 + t];
    if (t < 64) kmv[t] = kmean[b * C_ + h * 64 + t];
    #pragma unroll
    for (int ii = 0; ii < 2; ++ii) {
        int i = ii * 256 + t;               // 512 x uint4 = 4096 u16
        int r = i >> 3, c8 = (i & 7) * 8;
        uint4 v = *(const uint4*)&q[((size_t)(b * N_ + n0 + r)) * C_ + h * 64 + c8];
        float f[8];
        unpack8(v, f);
        #pragma unroll
        for (int j = 0; j < 8; ++j) qs[r * 68 + c8 + j] = f[j];
    }
    __syncthreads();

    // kv column e -> registers (stride-1 across lanes: conflict-free)
    float kvr[64];
    #pragma unroll
    for (int d = 0; d < 64; ++d) kvr[d] = kvs[d * 64 + e];

    if (t < 64) {
        float s = 1e-6f;
        #pragma unroll
        for (int d = 0; d < 64; ++d) s += qs[t * 68 + d] * kmv[d];
        zs[t] = 1.0f / s;
    }
    __syncthreads();

    for (int rr = 0; rr < 16; ++rr) {
        int r = rg * 16 + rr;
        float acc = 0.f;
        #pragma unroll
        for (int d = 0; d < 64; ++d) acc += qs[r * 68 + d] * kvr[d];
        y[((size_t)(b * N_ + n0 + r)) * C_ + h * 64 + e] = f2b(acc * zs[r]);
    }
}

// ---------------------------------------------------------------------------
// Depthwise 5x5 conv over v, add into y — channel-vectorized (uint4 = 8 bf16).
// ---------------------------------------------------------------------------
__global__ __launch_bounds__(256)
void conv_add(const u16* __restrict__ v, const void* __restrict__ w,
              const void* __restrict__ wb, u16* __restrict__ y,
              const int* __restrict__ flag)
{
    __shared__ float wt[25][64];
    __shared__ float bl[64];
    const int fmt = flag[0];
    const int t = threadIdx.x;
    for (int i = t; i < 1600; i += 256) {
        const int tap = i >> 6, c = i & 63;
        const int src = c * 25 + tap;
        wt[tap][c] = fmt ? ((const float*)w)[src] : b2f(((const u16*)w)[src]);
    }
    if (t < 64)
        bl[t] = fmt ? ((const float*)wb)[t] : b2f(((const u16*)wb)[t]);
    __syncthreads();

    const size_t gid = (size_t)blockIdx.x * 256 + t;   // 0 .. 2,097,151
    const int cg = (int)(gid & 127);                   // channel-group (8 ch)
    const int n  = (int)((gid >> 7) & 4095);           // pixel (wave-uniform)
    const int b  = (int)(gid >> 19);
    const int c0 = cg * 8;
    const int cb = c0 & 63;                            // weight channel base
    const int yp = n >> 6, xp = n & 63;

    float acc[8];
    #pragma unroll
    for (int j = 0; j < 8; ++j) acc[j] = bl[cb + j];

    const u16* vbase = v + (size_t)b * N_ * C_ + c0;
    #pragma unroll
    for (int dy = 0; dy < 5; ++dy) {
        const int yy = yp + dy - 2;
        if (yy < 0 || yy >= HW_) continue;
        #pragma unroll
        for (int dx = 0; dx < 5; ++dx) {
            const int xx = xp + dx - 2;
            if (xx < 0 || xx >= HW_) continue;
            uint4 pv = *(const uint4*)(vbase + (size_t)(yy * HW_ + xx) * C_);
            float f[8];
            unpack8(pv, f);
            const int tap = dy * 5 + dx;
            float4 w0 = *(const float4*)&wt[tap][cb];
            float4 w1 = *(const float4*)&wt[tap][cb + 4];
            acc[0] += w0.x * f[0]; acc[1] += w0.y * f[1];
            acc[2] += w0.z * f[2]; acc[3] += w0.w * f[3];
            acc[4] += w1.x * f[4]; acc[5] += w1.y * f[5];
            acc[6] += w1.z * f[6]; acc[7] += w1.w * f[7];
        }
    }

    uint4 yv = *(const uint4*)(y + gid * 8);
    float yf[8];
    unpack8(yv, yf);
    union { uint4 v4; u16 s[8]; } o;
    #pragma unroll
    for (int j = 0; j < 8; ++j) o.s[j] = f2b(yf[j] + acc[j]);
    *(uint4*)(y + gid * 8) = o.v4;
}

extern "C" void kernel_launch(void* const* d_in, const int* in_sizes, int n_in,
                              void* d_out, int out_size, void* d_ws, size_t ws_size,
                              hipStream_t stream)
{
    const void* x     = d_in[0];
    const void* Wq    = d_in[1];
    const void* Wkv   = d_in[2];
    const void* Wproj = d_in[3];
    const void* bproj = d_in[4];
    const void* dwc_w = d_in[5];
    const void* dwc_b = d_in[6];

    char* ws = (char*)d_ws;
    const size_t MI = 1024 * 1024;
    const size_t NEED_FAST = 35 * MI + 17 * 1024;
    // R7 finding: out_size is the fp32 ELEMENT count (16,777,216), not bytes
    // (harness does to_numpy(np.float32, (out_size,))). The output buffer is
    // NT_*C_ floats = 64 MB, enough for xb (32 MB) + kq (32 MB). This gate
    // passes under either convention (elements or bytes).
    const size_t OUT_ELEMS = (size_t)NT_ * C_;

    if (ws_size >= NEED_FAST && (size_t)out_size >= OUT_ELEMS) {
        // ---- fastest path: x pre-converted to bf16 -> all GEMMs use the
        //      ring-4 pipelined path (AEXT=0). ----
        u16*   vbuf  = (u16*)ws;
        u16*   WT    = (u16*)(ws + 32 * MI);
        float* kvh   = (float*)(ws + 34 * MI);
        float* kmean = (float*)(ws + 35 * MI);
        int*   flag  = (int*)(ws + 35 * MI + 16 * 1024);
        u16*   xb    = (u16*)d_out;                       // lower 32 MB of out
        u16*   kq    = (u16*)d_out + (size_t)NT_ * C_;    // upper 32 MB of out
        u16*   ybuf  = (u16*)ws;

        detect_fmt<<<1, 256, 0, stream>>>((const u16*)x, flag);
        zero_f32<<<dim3(1040), 256, 0, stream>>>(kvh, 266240);   // kvh + kmean contiguous
        convert_x<<<dim3(2048), 256, 0, stream>>>(x, xb, flag);

        // v = xb @ Wkv[:, C:]
        transpose_w<<<dim3(16, 16), 256, 0, stream>>>(Wkv, WT, flag, 2 * C_, C_, C_);
        gemm_mfma<0, 0, 0, 0><<<dim3(8, 128), 256, 0, stream>>>(xb, WT, vbuf, nullptr, flag, C_, C_);
        // k = relu(xb @ Wkv[:, :C]) + eps
        transpose_w<<<dim3(16, 16), 256, 0, stream>>>(Wkv, WT, flag, 2 * C_, 0, C_);
        gemm_mfma<1, 0, 0, 0><<<dim3(8, 128), 256, 0, stream>>>(xb, WT, kq, nullptr, flag, C_, C_);

        kmean_kernel<<<dim3(4, B_, 16), 256, 0, stream>>>(kq, kmean);
        kv_atomic<<<dim3(64, 8), 256, 0, stream>>>(kq, vbuf, kvh);

        // q = relu(xb @ Wq) + eps  (overwrites k; k dead, xb disjoint)
        transpose_w<<<dim3(16, 16), 256, 0, stream>>>(Wq, WT, flag, C_, 0, C_);
        gemm_mfma<1, 0, 0, 0><<<dim3(8, 128), 256, 0, stream>>>(xb, WT, kq, nullptr, flag, C_, C_);

        att_kernel<<<dim3(64, 64), 256, 0, stream>>>(kq, kvh, kmean, kq);
        conv_add<<<dim3(8192), 256, 0, stream>>>(vbuf, dwc_w, dwc_b, kq, flag);

        // move y into ws (v dead), then out = y @ Wproj + bproj (fp32 over all of d_out)
        hipMemcpyAsync(ws, kq, (size_t)NT_ * C_ * sizeof(u16), hipMemcpyDeviceToDevice, stream);
        transpose_w<<<dim3(16, 16), 256, 0, stream>>>(Wproj, WT, flag, C_, 0, C_);
        gemm_mfma<0, 1, 0, 1><<<dim3(8, 128), 256, 0, stream>>>(ybuf, WT, d_out, bproj, flag, C_, C_);
    } else if (ws_size >= NEED_FAST) {
        // ---- middle path (MFMA, fp32 A staged in-loop; AEXT=1 legacy) ----
        u16*   vbuf  = (u16*)ws;
        u16*   WT    = (u16*)(ws + 32 * MI);
        float* kvh   = (float*)(ws + 34 * MI);
        float* kmean = (float*)(ws + 35 * MI);
        int*   flag  = (int*)(ws + 35 * MI + 16 * 1024);
        u16*   kq    = (u16*)d_out;
        u16*   ybuf  = (u16*)ws;

        detect_fmt<<<1, 256, 0, stream>>>((const u16*)x, flag);
        zero_f32<<<dim3(1040), 256, 0, stream>>>(kvh, 266240);

        transpose_w<<<dim3(16, 16), 256, 0, stream>>>(Wkv, WT, flag, 2 * C_, C_, C_);
        gemm_mfma<0, 0, 1, 0><<<dim3(8, 128), 256, 0, stream>>>(x, WT, vbuf, nullptr, flag, C_, C_);
        transpose_w<<<dim3(16, 16), 256, 0, stream>>>(Wkv, WT, flag, 2 * C_, 0, C_);
        gemm_mfma<1, 0, 1, 0><<<dim3(8, 128), 256, 0, stream>>>(x, WT, kq, nullptr, flag, C_, C_);

        kmean_kernel<<<dim3(4, B_, 16), 256, 0, stream>>>(kq, kmean);
        kv_atomic<<<dim3(64, 8), 256, 0, stream>>>(kq, vbuf, kvh);

        transpose_w<<<dim3(16, 16), 256, 0, stream>>>(Wq, WT, flag, C_, 0, C_);
        gemm_mfma<1, 0, 1, 0><<<dim3(8, 128), 256, 0, stream>>>(x, WT, kq, nullptr, flag, C_, C_);

        att_kernel<<<dim3(64, 64), 256, 0, stream>>>(kq, kvh, kmean, kq);
        conv_add<<<dim3(8192), 256, 0, stream>>>(vbuf, dwc_w, dwc_b, kq, flag);

        hipMemcpyAsync(ws, d_out, (size_t)NT_ * C_ * sizeof(u16), hipMemcpyDeviceToDevice, stream);
        transpose_w<<<dim3(16, 16), 256, 0, stream>>>(Wproj, WT, flag, C_, 0, C_);
        gemm_mfma<0, 1, 0, 1><<<dim3(8, 128), 256, 0, stream>>>(ybuf, WT, d_out, bproj, flag, C_, C_);
    } else {
        // ---- fallback path (proven) ----
        u16*   vbuf  = (u16*)ws;
        float* kmean = (float*)(ws + 32 * MI);
        float* kvh   = (float*)(ws + 32 * MI + 16 * 1024);
        int*   flag  = (int*)(ws + 32 * MI + 16 * 1024 + 1 * MI);
        u16*   kq    = (u16*)d_out;
        u16*   ybuf  = (u16*)ws;

        detect_fmt<<<1, 256, 0, stream>>>((const u16*)x, flag);
        zero_f32<<<dim3(1040), 256, 0, stream>>>(kmean, 266240);

        gemm_any<0, 0, 1, 0><<<dim3(8, 128), 256, 0, stream>>>(x, Wkv, vbuf, nullptr, flag, NT_, C_, 2 * C_, C_, C_);
        gemm_any<1, 0, 1, 0><<<dim3(8, 128), 256, 0, stream>>>(x, Wkv, kq,   nullptr, flag, NT_, C_, 2 * C_, 0,  C_);

        kmean_kernel<<<dim3(4, B_, 16), 256, 0, stream>>>(kq, kmean);
        kv_atomic<<<dim3(64, 8), 256, 0, stream>>>(kq, vbuf, kvh);

        gemm_any<1, 0, 1, 0><<<dim3(8, 128), 256, 0, stream>>>(x, Wq, kq, nullptr, flag, NT_, C_, C_, 0, C_);

        att_kernel<<<dim3(64, 64), 256, 0, stream>>>(kq, kvh, kmean, kq);
        conv_add<<<dim3(8192), 256, 0, stream>>>(vbuf, dwc_w, dwc_b, kq, flag);

        hipMemcpyAsync(ws, d_out, (size_t)NT_ * C_ * sizeof(u16), hipMemcpyDeviceToDevice, stream);
        gemm_any<0, 1, 0, 1><<<dim3(8, 128), 256, 0, stream>>>(ybuf, Wproj, d_out, bproj, flag, NT_, C_, C_, 0, C_);
    }
}

// Round 10
// 529.929 us; speedup vs baseline: 1.2648x; 1.0833x over previous
//
#include <hip/hip_runtime.h>
#include <stdint.h>

typedef unsigned short u16;   // bf16 bits

#define B_   4
#define N_   4096
#define C_   1024
#define NT_  (B_*N_)          // 16384 rows
#define HW_  64               // H = W = 64

typedef __attribute__((ext_vector_type(8))) short bf16x8;
typedef __attribute__((ext_vector_type(4))) float f32x4;

__device__ __forceinline__ float b2f(u16 s) {
    union { uint32_t u; float f; } x; x.u = ((uint32_t)s) << 16; return x.f;
}
__device__ __forceinline__ u16 f2b(float f) {
    union { float f; uint32_t u; } x; x.f = f;
    uint32_t u = x.u;
    return (u16)((u + 0x7FFFu + ((u >> 16) & 1u)) >> 16);   // RNE
}
__device__ __forceinline__ float lo2f(uint32_t u) {
    union { uint32_t u; float f; } x; x.u = u << 16; return x.f;
}
__device__ __forceinline__ float hi2f(uint32_t u) {
    union { uint32_t u; float f; } x; x.u = u & 0xFFFF0000u; return x.f;
}
__device__ __forceinline__ void unpack8(uint4 v, float* f) {
    f[0] = lo2f(v.x); f[1] = hi2f(v.x); f[2] = lo2f(v.y); f[3] = hi2f(v.y);
    f[4] = lo2f(v.z); f[5] = hi2f(v.z); f[6] = lo2f(v.w); f[7] = hi2f(v.w);
}

// ---------------------------------------------------------------------------
// Input format detector (0 = bf16, 1 = fp32).
// ---------------------------------------------------------------------------
__global__ void detect_fmt(const u16* __restrict__ x, int* __restrict__ flag)
{
    __shared__ int smax[256];
    const int t = threadIdx.x;
    int m = 0;
    for (int i = t; i < 2048; i += 256) {
        int e = (x[2 * i] >> 7) & 0xFF;
        m = m > e ? m : e;
    }
    smax[t] = m;
    __syncthreads();
    for (int s = 128; s > 0; s >>= 1) {
        if (t < s) smax[t] = smax[t] > smax[t + s] ? smax[t] : smax[t + s];
        __syncthreads();
    }
    if (t == 0) flag[0] = (smax[0] >= 0x90) ? 1 : 0;
}

__global__ void zero_f32(float* p, int n) {
    int i = blockIdx.x * 256 + threadIdx.x;
    if (i < n) p[i] = 0.f;
}

// ---------------------------------------------------------------------------
// x (fp32 or bf16 per flag) -> bf16, one streaming pass.
// ---------------------------------------------------------------------------
__global__ __launch_bounds__(256)
void convert_x(const void* __restrict__ x, u16* __restrict__ xb,
               const int* __restrict__ flag)
{
    const int fmt = flag[0];
    const size_t total = (size_t)NT_ * C_ / 8;          // 2,097,152 vec8
    const size_t stride = (size_t)gridDim.x * 256;
    size_t i = (size_t)blockIdx.x * 256 + threadIdx.x;
    if (fmt) {
        for (; i < total; i += stride) {
            const float4* p = (const float4*)x + i * 2;
            float4 a = p[0], b = p[1];
            union { uint4 v; u16 s[8]; } o;
            o.s[0] = f2b(a.x); o.s[1] = f2b(a.y); o.s[2] = f2b(a.z); o.s[3] = f2b(a.w);
            o.s[4] = f2b(b.x); o.s[5] = f2b(b.y); o.s[6] = f2b(b.z); o.s[7] = f2b(b.w);
            ((uint4*)xb)[i] = o.v;
        }
    } else {
        for (; i < total; i += stride)
            ((uint4*)xb)[i] = ((const uint4*)x)[i];
    }
}

// ---------------------------------------------------------------------------
// Weight transpose: WT[n, k] = W[k, col0+n] as bf16. W fmt per flag.
// ---------------------------------------------------------------------------
__global__ __launch_bounds__(256)
void transpose_w(const void* __restrict__ W, u16* __restrict__ WT,
                 const int* __restrict__ flag, int ldw, int col0, int Kdim)
{
    __shared__ u16 tile[64][65];
    const int fmt = flag[0];
    const int n0 = blockIdx.x * 64, k0 = blockIdx.y * 64;
    const int t = threadIdx.x;
    const int c = t & 63, rg = t >> 6;
    #pragma unroll 4
    for (int i = 0; i < 16; ++i) {
        int r = rg * 16 + i;
        size_t gi = (size_t)(k0 + r) * ldw + col0 + n0 + c;
        tile[r][c] = fmt ? f2b(((const float*)W)[gi]) : ((const u16*)W)[gi];
    }
    __syncthreads();
    #pragma unroll 4
    for (int i = 0; i < 16; ++i) {
        int r = rg * 16 + i;
        WT[(size_t)(n0 + r) * Kdim + k0 + c] = tile[c][r];
    }
}

// ---------------------------------------------------------------------------
// MFMA GEMM: C[m, j] = sum_k A[m,k] * BT[j,k]   (BT: n-major bf16)
// 128x128 tile, 4 waves (2x2), 4x4 x mfma_f32_16x16x32_bf16 per wave.
//
// AEXT==0: ring-4 pipeline, 3 tiles in flight, counted vmcnt(12).
//   All buffer indices are compile-time literals; barriers are
//   asm volatile("s_barrier":::"memory") bracketed by sched_barrier(0);
//   setprio(1) around MFMA cluster. Correctness HW-validated R5-R9.
//   REQUIRES: K multiple of 128 (all call sites use K=1024).
// AEXT==1: legacy single-buffer 2-barrier structure (fp32 A support).
// ---------------------------------------------------------------------------
template<int RELU, int BIAS, int AEXT, int CEXT>
__global__ __launch_bounds__(256)
void gemm_mfma(const void* __restrict__ A, const u16* __restrict__ BT,
               void* __restrict__ Cout, const void* __restrict__ bias,
               const int* __restrict__ flag, int K, int ldc)
{
    __shared__ u16 As[AEXT ? 1 : 4][128 * 32];
    __shared__ u16 Bs[AEXT ? 1 : 4][128 * 32];
    const int fmt = flag[0];
    const int t    = threadIdx.x;
    const int lane = t & 63;
    const int w    = t >> 6;          // wave 0..3
    const int wm   = w >> 1, wn = w & 1;
    const int quad = lane >> 4;       // 0..3
    const int l16  = lane & 15;

    int bid = blockIdx.y * gridDim.x + blockIdx.x;
    const int nwg = gridDim.x * gridDim.y;
    if ((nwg & 7) == 0)
        bid = (bid & 7) * (nwg >> 3) + (bid >> 3);   // bijective chunked swizzle
    const int j0 = (bid % gridDim.x) * 128;
    const int m0 = (bid / gridDim.x) * 128;

    const int srow = lane >> 2;
    const int gseg = ((lane & 3) ^ ((lane >> 3) & 3)) * 8;

    f32x4 acc[4][4] = {};

    if (AEXT) {
        // -------- legacy path (handles fp32 A; single buffer, __syncthreads) --------
        for (int k0 = 0; k0 < K; k0 += 32) {
            if (fmt) {
                #pragma unroll
                for (int i = 0; i < 2; ++i) {
                    const int r0 = w * 32 + i * 16;
                    const float* gp = (const float*)A + (size_t)(m0 + r0 + srow) * K + k0 + gseg;
                    float4 f0 = *(const float4*)gp;
                    float4 f1 = *(const float4*)(gp + 4);
                    union { bf16x8 v; u16 s[8]; } o;
                    o.s[0] = f2b(f0.x); o.s[1] = f2b(f0.y); o.s[2] = f2b(f0.z); o.s[3] = f2b(f0.w);
                    o.s[4] = f2b(f1.x); o.s[5] = f2b(f1.y); o.s[6] = f2b(f1.z); o.s[7] = f2b(f1.w);
                    *(bf16x8*)&As[0][(r0 + srow) * 32 + (lane & 3) * 8] = o.v;
                }
            } else {
                #pragma unroll
                for (int i = 0; i < 2; ++i) {
                    const int r0 = w * 32 + i * 16;
                    const u16* gp = (const u16*)A + (size_t)(m0 + r0 + srow) * K + k0 + gseg;
                    __builtin_amdgcn_global_load_lds(
                        (const __attribute__((address_space(1))) void*)gp,
                        (__attribute__((address_space(3))) void*)&As[0][r0 * 32], 16, 0, 0);
                }
            }
            #pragma unroll
            for (int i = 0; i < 2; ++i) {
                const int r0 = w * 32 + i * 16;
                const u16* gp = BT + (size_t)(j0 + r0 + srow) * K + k0 + gseg;
                __builtin_amdgcn_global_load_lds(
                    (const __attribute__((address_space(1))) void*)gp,
                    (__attribute__((address_space(3))) void*)&Bs[0][r0 * 32], 16, 0, 0);
            }
            __syncthreads();

            bf16x8 af[4], bfr[4];
            #pragma unroll
            for (int mt = 0; mt < 4; ++mt) {
                const int r = wm * 64 + mt * 16 + l16;
                const int slot = quad ^ ((r >> 1) & 3);
                af[mt] = *(const bf16x8*)&As[0][r * 32 + slot * 8];
            }
            #pragma unroll
            for (int nt = 0; nt < 4; ++nt) {
                const int r = wn * 64 + nt * 16 + l16;
                const int slot = quad ^ ((r >> 1) & 3);
                bfr[nt] = *(const bf16x8*)&Bs[0][r * 32 + slot * 8];
            }
            #pragma unroll
            for (int mt = 0; mt < 4; ++mt)
                #pragma unroll
                for (int nt = 0; nt < 4; ++nt)
                    acc[mt][nt] = __builtin_amdgcn_mfma_f32_16x16x32_bf16(
                        af[mt], bfr[nt], acc[mt][nt], 0, 0, 0);
            __syncthreads();
        }
    } else {
        // -------- ring-4 counted-vmcnt pipeline (A, B both bf16) --------
        auto stage = [&](int buf, int tile) {
            const int kk = tile * 32;
            #pragma unroll
            for (int i = 0; i < 2; ++i) {
                const int r0 = w * 32 + i * 16;
                const u16* gp = (const u16*)A + (size_t)(m0 + r0 + srow) * K + kk + gseg;
                __builtin_amdgcn_global_load_lds(
                    (const __attribute__((address_space(1))) void*)gp,
                    (__attribute__((address_space(3))) void*)&As[buf][r0 * 32], 16, 0, 0);
            }
            #pragma unroll
            for (int i = 0; i < 2; ++i) {
                const int r0 = w * 32 + i * 16;
                const u16* gp = BT + (size_t)(j0 + r0 + srow) * K + kk + gseg;
                __builtin_amdgcn_global_load_lds(
                    (const __attribute__((address_space(1))) void*)gp,
                    (__attribute__((address_space(3))) void*)&Bs[buf][r0 * 32], 16, 0, 0);
            }
        };
        auto compute = [&](int buf) {
            bf16x8 af[4], bfr[4];
            #pragma unroll
            for (int mt = 0; mt < 4; ++mt) {
                const int r = wm * 64 + mt * 16 + l16;
                const int slot = quad ^ ((r >> 1) & 3);
                af[mt] = *(const bf16x8*)&As[buf][r * 32 + slot * 8];
            }
            #pragma unroll
            for (int nt = 0; nt < 4; ++nt) {
                const int r = wn * 64 + nt * 16 + l16;
                const int slot = quad ^ ((r >> 1) & 3);
                bfr[nt] = *(const bf16x8*)&Bs[buf][r * 32 + slot * 8];
            }
            __builtin_amdgcn_s_setprio(1);
            #pragma unroll
            for (int mt = 0; mt < 4; ++mt)
                #pragma unroll
                for (int nt = 0; nt < 4; ++nt)
                    acc[mt][nt] = __builtin_amdgcn_mfma_f32_16x16x32_bf16(
                        af[mt], bfr[nt], acc[mt][nt], 0, 0, 0);
            __builtin_amdgcn_s_setprio(0);
        };
        #define GBAR() do {                                   \
            __builtin_amdgcn_sched_barrier(0);                \
            asm volatile("s_barrier" ::: "memory");           \
            __builtin_amdgcn_sched_barrier(0);                \
        } while (0)

        const int nsteps = K >> 5;        // 32-wide K tiles; nsteps % 4 == 0
        // prologue: 3 tiles in flight (12 loads/wave)
        stage(0, 0); stage(1, 1); stage(2, 2);

        int tt = 0;
        for (; tt + 4 < nsteps; tt += 4) {
            stage(3, tt + 3);
            asm volatile("s_waitcnt vmcnt(12)" ::: "memory");
            GBAR(); compute(0); GBAR();
            stage(0, tt + 4);
            asm volatile("s_waitcnt vmcnt(12)" ::: "memory");
            GBAR(); compute(1); GBAR();
            stage(1, tt + 5);
            asm volatile("s_waitcnt vmcnt(12)" ::: "memory");
            GBAR(); compute(2); GBAR();
            stage(2, tt + 6);
            asm volatile("s_waitcnt vmcnt(12)" ::: "memory");
            GBAR(); compute(3); GBAR();
        }
        // tail: tt == nsteps-4; stage last tile, then drain 12 -> 8 -> 4 -> 0
        stage(3, tt + 3);
        asm volatile("s_waitcnt vmcnt(12)" ::: "memory");
        GBAR(); compute(0); GBAR();
        asm volatile("s_waitcnt vmcnt(8)" ::: "memory");
        GBAR(); compute(1); GBAR();
        asm volatile("s_waitcnt vmcnt(4)" ::: "memory");
        GBAR(); compute(2); GBAR();
        asm volatile("s_waitcnt vmcnt(0)" ::: "memory");
        GBAR(); compute(3);
        #undef GBAR
    }

    #pragma unroll
    for (int mt = 0; mt < 4; ++mt) {
        #pragma unroll
        for (int nt = 0; nt < 4; ++nt) {
            const int col = j0 + wn * 64 + nt * 16 + l16;
            float bv = 0.f;
            if (BIAS) bv = fmt ? ((const float*)bias)[col] : b2f(((const u16*)bias)[col]);
            #pragma unroll
            for (int r = 0; r < 4; ++r) {
                const int row = m0 + wm * 64 + mt * 16 + quad * 4 + r;
                float v = acc[mt][nt][r];
                if (BIAS) v += bv;
                if (RELU) v = fmaxf(v, 0.f) + 1e-6f;
                if (CEXT && fmt) ((float*)Cout)[(size_t)row * ldc + col] = v;
                else             ((u16*)Cout)[(size_t)row * ldc + col] = f2b(v);
            }
        }
    }
}

// ---------------------------------------------------------------------------
// Fallback VALU GEMM (proven) — used only if ws_size is too small.
// ---------------------------------------------------------------------------
template<int RELU, int BIAS, int AEXT, int CEXT>
__global__ __launch_bounds__(256)
void gemm_any(const void* __restrict__ A, const void* __restrict__ Bm,
              void* __restrict__ Cout, const void* __restrict__ bias,
              const int* __restrict__ flag,
              int M, int K, int ldb, int bcol0, int ldc)
{
    const int fmt = flag[0];
    __shared__ float As[16][128];
    __shared__ float Bs[16][128];
    const int t  = threadIdx.x;
    const int tx = t & 15, ty = t >> 4;
    const int m0 = blockIdx.y * 128;
    const int j0 = blockIdx.x * 128;
    const int la_row = t >> 1;
    const int la_k   = (t & 1) * 8;
    const int lb_k   = t >> 4;
    const int lb_j   = (t & 15) * 8;

    float acc[8][8];
    #pragma unroll
    for (int i = 0; i < 8; ++i)
        #pragma unroll
        for (int j = 0; j < 8; ++j) acc[i][j] = 0.f;

    for (int k0 = 0; k0 < K; k0 += 16) {
        float af[8], bfv[8];
        if (AEXT && fmt) {
            const float* ap = (const float*)A + (size_t)(m0 + la_row) * K + k0 + la_k;
            float4 a0 = *(const float4*)ap;
            float4 a1 = *(const float4*)(ap + 4);
            af[0] = a0.x; af[1] = a0.y; af[2] = a0.z; af[3] = a0.w;
            af[4] = a1.x; af[5] = a1.y; af[6] = a1.z; af[7] = a1.w;
        } else {
            uint4 av = *(const uint4*)((const u16*)A + (size_t)(m0 + la_row) * K + k0 + la_k);
            unpack8(av, af);
        }
        if (fmt) {
            const float* bp = (const float*)Bm + (size_t)(k0 + lb_k) * ldb + bcol0 + j0 + lb_j;
            float4 b0 = *(const float4*)bp;
            float4 b1 = *(const float4*)(bp + 4);
            bfv[0] = b0.x; bfv[1] = b0.y; bfv[2] = b0.z; bfv[3] = b0.w;
            bfv[4] = b1.x; bfv[5] = b1.y; bfv[6] = b1.z; bfv[7] = b1.w;
        } else {
            uint4 bv = *(const uint4*)((const u16*)Bm + (size_t)(k0 + lb_k) * ldb + bcol0 + j0 + lb_j);
            unpack8(bv, bfv);
        }
        __syncthreads();
        #pragma unroll
        for (int i = 0; i < 8; ++i) As[la_k + i][la_row] = af[i];
        *(float4*)&Bs[lb_k][lb_j]     = make_float4(bfv[0], bfv[1], bfv[2], bfv[3]);
        *(float4*)&Bs[lb_k][lb_j + 4] = make_float4(bfv[4], bfv[5], bfv[6], bfv[7]);
        __syncthreads();
        #pragma unroll
        for (int kk = 0; kk < 16; ++kk) {
            float a[8], b[8];
            *(float4*)&a[0] = *(const float4*)&As[kk][ty * 8];
            *(float4*)&a[4] = *(const float4*)&As[kk][ty * 8 + 4];
            *(float4*)&b[0] = *(const float4*)&Bs[kk][tx * 8];
            *(float4*)&b[4] = *(const float4*)&Bs[kk][tx * 8 + 4];
            #pragma unroll
            for (int i = 0; i < 8; ++i)
                #pragma unroll
                for (int j = 0; j < 8; ++j)
                    acc[i][j] += a[i] * b[j];
        }
    }

    #pragma unroll
    for (int i = 0; i < 8; ++i) {
        const int m = m0 + ty * 8 + i;
        float vals[8];
        #pragma unroll
        for (int j = 0; j < 8; ++j) {
            float v = acc[i][j];
            if (BIAS) {
                const int bi = j0 + tx * 8 + j;
                v += fmt ? ((const float*)bias)[bi] : b2f(((const u16*)bias)[bi]);
            }
            if (RELU) v = fmaxf(v, 0.f) + 1e-6f;
            vals[j] = v;
        }
        if (CEXT && fmt) {
            float* cp = (float*)Cout + (size_t)m * ldc + j0 + tx * 8;
            *(float4*)cp       = make_float4(vals[0], vals[1], vals[2], vals[3]);
            *(float4*)(cp + 4) = make_float4(vals[4], vals[5], vals[6], vals[7]);
        } else {
            union { uint4 v; u16 s[8]; } o;
            #pragma unroll
            for (int j = 0; j < 8; ++j) o.s[j] = f2b(vals[j]);
            *(uint4*)((u16*)Cout + (size_t)m * ldc + j0 + tx * 8) = o.v;
        }
    }
}

// ---------------------------------------------------------------------------
// kv_atomic (R10 rewrite): kvh[bh, d*64+e] += (1/N) sum_n k*v over a 512-row
// chunk; also accumulates the k-channel-mean (fuses old kmean_kernel — kv
// already reads every element of k).
//  - uint4 (8x bf16) coalesced loads, 32 rows/round, 16 rounds (was 128
//    rounds of scalar 2B loads) -> 32 barriers instead of 256.
//  - register prefetch of next round's uint4s issued before compute ->
//    HBM latency hides under the 512 FMAs/round.
//  - LDS access: vv[r][e] stride-1 (2 lanes/bank = free); kk[r][d0+i]
//    wave-uniform broadcast (free).
// ---------------------------------------------------------------------------
__global__ __launch_bounds__(256)
void kv_atomic(const u16* __restrict__ k, const u16* __restrict__ v,
               float* __restrict__ kvh, float* __restrict__ km)
{
    __shared__ float kk[32][64];
    __shared__ float vv[32][64];
    const int bh = blockIdx.x;
    const int ch = blockIdx.y;
    const int b = bh >> 4, h = bh & 15;
    const int t = threadIdx.x;
    const int e = t & 63, d0 = (t >> 6) * 16;
    const int lr = t >> 3;            // 0..31: row within round
    const int lc = (t & 7) * 8;       // channel-8 base
    const int n0 = ch * 512;

    float acc[16];
    #pragma unroll
    for (int i = 0; i < 16; ++i) acc[i] = 0.f;
    float ksum[8];
    #pragma unroll
    for (int j = 0; j < 8; ++j) ksum[j] = 0.f;

    const u16* kbase = k + ((size_t)(b * N_ + n0 + lr)) * C_ + h * 64 + lc;
    const u16* vbase = v + ((size_t)(b * N_ + n0 + lr)) * C_ + h * 64 + lc;

    uint4 kreg = *(const uint4*)kbase;
    uint4 vreg = *(const uint4*)vbase;

    for (int rd = 0; rd < 16; ++rd) {
        float kf[8], vf[8];
        unpack8(kreg, kf);
        unpack8(vreg, vf);
        if (rd + 1 < 16) {            // prefetch next round (hides under compute)
            kreg = *(const uint4*)(kbase + (size_t)(rd + 1) * 32 * C_);
            vreg = *(const uint4*)(vbase + (size_t)(rd + 1) * 32 * C_);
        }
        #pragma unroll
        for (int j = 0; j < 8; ++j) ksum[j] += kf[j];
        __syncthreads();              // prior round's LDS reads complete
        #pragma unroll
        for (int j = 0; j < 8; ++j) { kk[lr][lc + j] = kf[j]; vv[lr][lc + j] = vf[j]; }
        __syncthreads();
        #pragma unroll
        for (int r = 0; r < 32; ++r) {
            float ve = vv[r][e];
            #pragma unroll
            for (int i = 0; i < 16; ++i) acc[i] += kk[r][d0 + i] * ve;
        }
    }

    float* dst = kvh + (size_t)bh * 4096;
    #pragma unroll
    for (int i = 0; i < 16; ++i)
        atomicAdd(&dst[(d0 + i) * 64 + e], acc[i] * (1.0f / N_));

    // fused kmean: reduce the 32 row-groups per channel via LDS, 64 atomics/block
    __syncthreads();
    #pragma unroll
    for (int j = 0; j < 8; ++j) kk[lr][lc + j] = ksum[j];
    __syncthreads();
    if (t < 64) {
        float s = 0.f;
        #pragma unroll
        for (int r = 0; r < 32; ++r) s += kk[r][t];
        atomicAdd(&km[b * C_ + h * 64 + t], s * (1.0f / N_));
    }
}

// ---------------------------------------------------------------------------
// att: y = (q @ KV_h) * z.   kv column e held in 64 VGPRs (reused over all
// 16 rows) -> inner loop is wave-uniform ds_read_b128 of qs + VALU FMA.
// ---------------------------------------------------------------------------
__global__ __launch_bounds__(256)
void att_kernel(const u16* __restrict__ q, const float* __restrict__ kvh,
                const float* __restrict__ kmean, u16* __restrict__ y)
{
    __shared__ float kvs[64 * 64];
    __shared__ float qs[64 * 68];     // 68-float pitch: 272 B, 16B-aligned rows
    __shared__ float kmv[64];
    __shared__ float zs[64];
    const int bh = blockIdx.y;
    const int b = bh >> 4, h = bh & 15;
    const int n0 = blockIdx.x * 64;
    const int t = threadIdx.x;
    const int e = t & 63, rg = t >> 6;

    // cooperative loads (vectorized)
    const float4* kvsrc4 = (const float4*)(kvh + (size_t)bh * 4096);
    #pragma unroll
    for (int i = 0; i < 4; ++i)
        *(float4*)&kvs[(i * 256 + t) * 4] = kvsrc4[i * 256 + t];
    if (t < 64) kmv[t] = kmean[b * C_ + h * 64 + t];
    #pragma unroll
    for (int ii = 0; ii < 2; ++ii) {
        int i = ii * 256 + t;               // 512 x uint4 = 4096 u16
        int r = i >> 3, c8 = (i & 7) * 8;
        uint4 v = *(const uint4*)&q[((size_t)(b * N_ + n0 + r)) * C_ + h * 64 + c8];
        float f[8];
        unpack8(v, f);
        #pragma unroll
        for (int j = 0; j < 8; ++j) qs[r * 68 + c8 + j] = f[j];
    }
    __syncthreads();

    // kv column e -> registers (stride-1 across lanes: conflict-free)
    float kvr[64];
    #pragma unroll
    for (int d = 0; d < 64; ++d) kvr[d] = kvs[d * 64 + e];

    if (t < 64) {
        float s = 1e-6f;
        #pragma unroll
        for (int d = 0; d < 64; ++d) s += qs[t * 68 + d] * kmv[d];
        zs[t] = 1.0f / s;
    }
    __syncthreads();

    for (int rr = 0; rr < 16; ++rr) {
        int r = rg * 16 + rr;
        float acc = 0.f;
        #pragma unroll
        for (int d = 0; d < 64; ++d) acc += qs[r * 68 + d] * kvr[d];
        y[((size_t)(b * N_ + n0 + r)) * C_ + h * 64 + e] = f2b(acc * zs[r]);
    }
}

// ---------------------------------------------------------------------------
// Depthwise 5x5 conv over v, add into y — channel-vectorized (uint4 = 8 bf16).
// ---------------------------------------------------------------------------
__global__ __launch_bounds__(256)
void conv_add(const u16* __restrict__ v, const void* __restrict__ w,
              const void* __restrict__ wb, u16* __restrict__ y,
              const int* __restrict__ flag)
{
    __shared__ float wt[25][64];
    __shared__ float bl[64];
    const int fmt = flag[0];
    const int t = threadIdx.x;
    for (int i = t; i < 1600; i += 256) {
        const int tap = i >> 6, c = i & 63;
        const int src = c * 25 + tap;
        wt[tap][c] = fmt ? ((const float*)w)[src] : b2f(((const u16*)w)[src]);
    }
    if (t < 64)
        bl[t] = fmt ? ((const float*)wb)[t] : b2f(((const u16*)wb)[t]);
    __syncthreads();

    const size_t gid = (size_t)blockIdx.x * 256 + t;   // 0 .. 2,097,151
    const int cg = (int)(gid & 127);                   // channel-group (8 ch)
    const int n  = (int)((gid >> 7) & 4095);           // pixel (wave-uniform)
    const int b  = (int)(gid >> 19);
    const int c0 = cg * 8;
    const int cb = c0 & 63;                            // weight channel base
    const int yp = n >> 6, xp = n & 63;

    float acc[8];
    #pragma unroll
    for (int j = 0; j < 8; ++j) acc[j] = bl[cb + j];

    const u16* vbase = v + (size_t)b * N_ * C_ + c0;
    #pragma unroll
    for (int dy = 0; dy < 5; ++dy) {
        const int yy = yp + dy - 2;
        if (yy < 0 || yy >= HW_) continue;
        #pragma unroll
        for (int dx = 0; dx < 5; ++dx) {
            const int xx = xp + dx - 2;
            if (xx < 0 || xx >= HW_) continue;
            uint4 pv = *(const uint4*)(vbase + (size_t)(yy * HW_ + xx) * C_);
            float f[8];
            unpack8(pv, f);
            const int tap = dy * 5 + dx;
            float4 w0 = *(const float4*)&wt[tap][cb];
            float4 w1 = *(const float4*)&wt[tap][cb + 4];
            acc[0] += w0.x * f[0]; acc[1] += w0.y * f[1];
            acc[2] += w0.z * f[2]; acc[3] += w0.w * f[3];
            acc[4] += w1.x * f[4]; acc[5] += w1.y * f[5];
            acc[6] += w1.z * f[6]; acc[7] += w1.w * f[7];
        }
    }

    uint4 yv = *(const uint4*)(y + gid * 8);
    float yf[8];
    unpack8(yv, yf);
    union { uint4 v4; u16 s[8]; } o;
    #pragma unroll
    for (int j = 0; j < 8; ++j) o.s[j] = f2b(yf[j] + acc[j]);
    *(uint4*)(y + gid * 8) = o.v4;
}

extern "C" void kernel_launch(void* const* d_in, const int* in_sizes, int n_in,
                              void* d_out, int out_size, void* d_ws, size_t ws_size,
                              hipStream_t stream)
{
    const void* x     = d_in[0];
    const void* Wq    = d_in[1];
    const void* Wkv   = d_in[2];
    const void* Wproj = d_in[3];
    const void* bproj = d_in[4];
    const void* dwc_w = d_in[5];
    const void* dwc_b = d_in[6];

    char* ws = (char*)d_ws;
    const size_t MI = 1024 * 1024;
    const size_t NEED_FAST = 35 * MI + 17 * 1024;
    // out_size is the fp32 ELEMENT count (R7 finding); gate passes under
    // either convention (elements or bytes).
    const size_t OUT_ELEMS = (size_t)NT_ * C_;

    if (ws_size >= NEED_FAST && (size_t)out_size >= OUT_ELEMS) {
        // ---- fastest path: x pre-converted to bf16 -> all GEMMs use the
        //      ring-4 pipelined path (AEXT=0). ----
        u16*   vbuf  = (u16*)ws;
        u16*   WT    = (u16*)(ws + 32 * MI);
        float* kvh   = (float*)(ws + 34 * MI);
        float* kmean = (float*)(ws + 35 * MI);
        int*   flag  = (int*)(ws + 35 * MI + 16 * 1024);
        u16*   xb    = (u16*)d_out;                       // lower 32 MB of out
        u16*   kq    = (u16*)d_out + (size_t)NT_ * C_;    // upper 32 MB of out
        u16*   ybuf  = (u16*)ws;

        detect_fmt<<<1, 256, 0, stream>>>((const u16*)x, flag);
        zero_f32<<<dim3(1040), 256, 0, stream>>>(kvh, 266240);   // kvh + kmean contiguous
        convert_x<<<dim3(2048), 256, 0, stream>>>(x, xb, flag);

        // v = xb @ Wkv[:, C:]
        transpose_w<<<dim3(16, 16), 256, 0, stream>>>(Wkv, WT, flag, 2 * C_, C_, C_);
        gemm_mfma<0, 0, 0, 0><<<dim3(8, 128), 256, 0, stream>>>(xb, WT, vbuf, nullptr, flag, C_, C_);
        // k = relu(xb @ Wkv[:, :C]) + eps
        transpose_w<<<dim3(16, 16), 256, 0, stream>>>(Wkv, WT, flag, 2 * C_, 0, C_);
        gemm_mfma<1, 0, 0, 0><<<dim3(8, 128), 256, 0, stream>>>(xb, WT, kq, nullptr, flag, C_, C_);

        kv_atomic<<<dim3(64, 8), 256, 0, stream>>>(kq, vbuf, kvh, kmean);

        // q = relu(xb @ Wq) + eps  (overwrites k; k dead, xb disjoint)
        transpose_w<<<dim3(16, 16), 256, 0, stream>>>(Wq, WT, flag, C_, 0, C_);
        gemm_mfma<1, 0, 0, 0><<<dim3(8, 128), 256, 0, stream>>>(xb, WT, kq, nullptr, flag, C_, C_);

        att_kernel<<<dim3(64, 64), 256, 0, stream>>>(kq, kvh, kmean, kq);
        conv_add<<<dim3(8192), 256, 0, stream>>>(vbuf, dwc_w, dwc_b, kq, flag);

        // move y into ws (v dead), then out = y @ Wproj + bproj (fp32 over all of d_out)
        hipMemcpyAsync(ws, kq, (size_t)NT_ * C_ * sizeof(u16), hipMemcpyDeviceToDevice, stream);
        transpose_w<<<dim3(16, 16), 256, 0, stream>>>(Wproj, WT, flag, C_, 0, C_);
        gemm_mfma<0, 1, 0, 1><<<dim3(8, 128), 256, 0, stream>>>(ybuf, WT, d_out, bproj, flag, C_, C_);
    } else if (ws_size >= NEED_FAST) {
        // ---- middle path (MFMA, fp32 A staged in-loop; AEXT=1 legacy) ----
        u16*   vbuf  = (u16*)ws;
        u16*   WT    = (u16*)(ws + 32 * MI);
        float* kvh   = (float*)(ws + 34 * MI);
        float* kmean = (float*)(ws + 35 * MI);
        int*   flag  = (int*)(ws + 35 * MI + 16 * 1024);
        u16*   kq    = (u16*)d_out;
        u16*   ybuf  = (u16*)ws;

        detect_fmt<<<1, 256, 0, stream>>>((const u16*)x, flag);
        zero_f32<<<dim3(1040), 256, 0, stream>>>(kvh, 266240);

        transpose_w<<<dim3(16, 16), 256, 0, stream>>>(Wkv, WT, flag, 2 * C_, C_, C_);
        gemm_mfma<0, 0, 1, 0><<<dim3(8, 128), 256, 0, stream>>>(x, WT, vbuf, nullptr, flag, C_, C_);
        transpose_w<<<dim3(16, 16), 256, 0, stream>>>(Wkv, WT, flag, 2 * C_, 0, C_);
        gemm_mfma<1, 0, 1, 0><<<dim3(8, 128), 256, 0, stream>>>(x, WT, kq, nullptr, flag, C_, C_);

        kv_atomic<<<dim3(64, 8), 256, 0, stream>>>(kq, vbuf, kvh, kmean);

        transpose_w<<<dim3(16, 16), 256, 0, stream>>>(Wq, WT, flag, C_, 0, C_);
        gemm_mfma<1, 0, 1, 0><<<dim3(8, 128), 256, 0, stream>>>(x, WT, kq, nullptr, flag, C_, C_);

        att_kernel<<<dim3(64, 64), 256, 0, stream>>>(kq, kvh, kmean, kq);
        conv_add<<<dim3(8192), 256, 0, stream>>>(vbuf, dwc_w, dwc_b, kq, flag);

        hipMemcpyAsync(ws, d_out, (size_t)NT_ * C_ * sizeof(u16), hipMemcpyDeviceToDevice, stream);
        transpose_w<<<dim3(16, 16), 256, 0, stream>>>(Wproj, WT, flag, C_, 0, C_);
        gemm_mfma<0, 1, 0, 1><<<dim3(8, 128), 256, 0, stream>>>(ybuf, WT, d_out, bproj, flag, C_, C_);
    } else {
        // ---- fallback path (proven) ----
        u16*   vbuf  = (u16*)ws;
        float* kmean = (float*)(ws + 32 * MI);
        float* kvh   = (float*)(ws + 32 * MI + 16 * 1024);
        int*   flag  = (int*)(ws + 32 * MI + 16 * 1024 + 1 * MI);
        u16*   kq    = (u16*)d_out;
        u16*   ybuf  = (u16*)ws;

        detect_fmt<<<1, 256, 0, stream>>>((const u16*)x, flag);
        zero_f32<<<dim3(1040), 256, 0, stream>>>(kmean, 266240);

        gemm_any<0, 0, 1, 0><<<dim3(8, 128), 256, 0, stream>>>(x, Wkv, vbuf, nullptr, flag, NT_, C_, 2 * C_, C_, C_);
        gemm_any<1, 0, 1, 0><<<dim3(8, 128), 256, 0, stream>>>(x, Wkv, kq,   nullptr, flag, NT_, C_, 2 * C_, 0,  C_);

        kv_atomic<<<dim3(64, 8), 256, 0, stream>>>(kq, vbuf, kvh, kmean);

        gemm_any<1, 0, 1, 0><<<dim3(8, 128), 256, 0, stream>>>(x, Wq, kq, nullptr, flag, NT_, C_, C_, 0, C_);

        att_kernel<<<dim3(64, 64), 256, 0, stream>>>(kq, kvh, kmean, kq);
        conv_add<<<dim3(8192), 256, 0, stream>>>(vbuf, dwc_w, dwc_b, kq, flag);

        hipMemcpyAsync(ws, d_out, (size_t)NT_ * C_ * sizeof(u16), hipMemcpyDeviceToDevice, stream);
        gemm_any<0, 1, 0, 1><<<dim3(8, 128), 256, 0, stream>>>(ybuf, Wproj, d_out, bproj, flag, NT_, C_, C_, 0, C_);
    }
}

// Round 12
// 491.040 us; speedup vs baseline: 1.3650x; 1.0792x over previous
//
#include <hip/hip_runtime.h>
#include <stdint.h>

typedef unsigned short u16;   // bf16 bits

#define B_   4
#define N_   4096
#define C_   1024
#define NT_  (B_*N_)          // 16384 rows
#define HW_  64               // H = W = 64

typedef __attribute__((ext_vector_type(8))) short bf16x8;
typedef __attribute__((ext_vector_type(4))) float f32x4;

__device__ __forceinline__ float b2f(u16 s) {
    union { uint32_t u; float f; } x; x.u = ((uint32_t)s) << 16; return x.f;
}
__device__ __forceinline__ u16 f2b(float f) {
    union { float f; uint32_t u; } x; x.f = f;
    uint32_t u = x.u;
    return (u16)((u + 0x7FFFu + ((u >> 16) & 1u)) >> 16);   // RNE
}
__device__ __forceinline__ float lo2f(uint32_t u) {
    union { uint32_t u; float f; } x; x.u = u << 16; return x.f;
}
__device__ __forceinline__ float hi2f(uint32_t u) {
    union { uint32_t u; float f; } x; x.u = u & 0xFFFF0000u; return x.f;
}
__device__ __forceinline__ void unpack8(uint4 v, float* f) {
    f[0] = lo2f(v.x); f[1] = hi2f(v.x); f[2] = lo2f(v.y); f[3] = hi2f(v.y);
    f[4] = lo2f(v.z); f[5] = hi2f(v.z); f[6] = lo2f(v.w); f[7] = hi2f(v.w);
}

// ---------------------------------------------------------------------------
// Input format detector (0 = bf16, 1 = fp32).
// ---------------------------------------------------------------------------
__global__ void detect_fmt(const u16* __restrict__ x, int* __restrict__ flag)
{
    __shared__ int smax[256];
    const int t = threadIdx.x;
    int m = 0;
    for (int i = t; i < 2048; i += 256) {
        int e = (x[2 * i] >> 7) & 0xFF;
        m = m > e ? m : e;
    }
    smax[t] = m;
    __syncthreads();
    for (int s = 128; s > 0; s >>= 1) {
        if (t < s) smax[t] = smax[t] > smax[t + s] ? smax[t] : smax[t + s];
        __syncthreads();
    }
    if (t == 0) flag[0] = (smax[0] >= 0x90) ? 1 : 0;
}

__global__ void zero_f32(float* p, int n) {
    int i = blockIdx.x * 256 + threadIdx.x;
    if (i < n) p[i] = 0.f;
}

// ---------------------------------------------------------------------------
// x (fp32 or bf16 per flag) -> bf16, one streaming pass.
// ---------------------------------------------------------------------------
__global__ __launch_bounds__(256)
void convert_x(const void* __restrict__ x, u16* __restrict__ xb,
               const int* __restrict__ flag)
{
    const int fmt = flag[0];
    const size_t total = (size_t)NT_ * C_ / 8;          // 2,097,152 vec8
    const size_t stride = (size_t)gridDim.x * 256;
    size_t i = (size_t)blockIdx.x * 256 + threadIdx.x;
    if (fmt) {
        for (; i < total; i += stride) {
            const float4* p = (const float4*)x + i * 2;
            float4 a = p[0], b = p[1];
            union { uint4 v; u16 s[8]; } o;
            o.s[0] = f2b(a.x); o.s[1] = f2b(a.y); o.s[2] = f2b(a.z); o.s[3] = f2b(a.w);
            o.s[4] = f2b(b.x); o.s[5] = f2b(b.y); o.s[6] = f2b(b.z); o.s[7] = f2b(b.w);
            ((uint4*)xb)[i] = o.v;
        }
    } else {
        for (; i < total; i += stride)
            ((uint4*)xb)[i] = ((const uint4*)x)[i];
    }
}

// ---------------------------------------------------------------------------
// Weight transpose: WT[n, k] = W[k, col0+n] as bf16. W fmt per flag.
// ---------------------------------------------------------------------------
__global__ __launch_bounds__(256)
void transpose_w(const void* __restrict__ W, u16* __restrict__ WT,
                 const int* __restrict__ flag, int ldw, int col0, int Kdim)
{
    __shared__ u16 tile[64][65];
    const int fmt = flag[0];
    const int n0 = blockIdx.x * 64, k0 = blockIdx.y * 64;
    const int t = threadIdx.x;
    const int c = t & 63, rg = t >> 6;
    #pragma unroll 4
    for (int i = 0; i < 16; ++i) {
        int r = rg * 16 + i;
        size_t gi = (size_t)(k0 + r) * ldw + col0 + n0 + c;
        tile[r][c] = fmt ? f2b(((const float*)W)[gi]) : ((const u16*)W)[gi];
    }
    __syncthreads();
    #pragma unroll 4
    for (int i = 0; i < 16; ++i) {
        int r = rg * 16 + i;
        WT[(size_t)(n0 + r) * Kdim + k0 + c] = tile[c][r];
    }
}

// ---------------------------------------------------------------------------
// MFMA GEMM: C[m, j] = sum_k A[m,k] * BT[j,k]   (BT: n-major bf16)
// 128x128 tile, 4 waves (2x2), 4x4 x mfma_f32_16x16x32_bf16 per wave.
//
// AEXT==0: ring-4 pipeline, 3 tiles in flight, counted vmcnt(12).
//   All buffer indices are compile-time literals; barriers are
//   asm volatile("s_barrier":::"memory") bracketed by sched_barrier(0);
//   setprio(1) around MFMA cluster. Correctness HW-validated R5-R10.
//   REQUIRES: K multiple of 128 (all call sites use K=1024).
// AEXT==1: legacy single-buffer 2-barrier structure (fp32 A support).
// ---------------------------------------------------------------------------
template<int RELU, int BIAS, int AEXT, int CEXT>
__global__ __launch_bounds__(256)
void gemm_mfma(const void* __restrict__ A, const u16* __restrict__ BT,
               void* __restrict__ Cout, const void* __restrict__ bias,
               const int* __restrict__ flag, int K, int ldc)
{
    __shared__ u16 As[AEXT ? 1 : 4][128 * 32];
    __shared__ u16 Bs[AEXT ? 1 : 4][128 * 32];
    const int fmt = flag[0];
    const int t    = threadIdx.x;
    const int lane = t & 63;
    const int w    = t >> 6;          // wave 0..3
    const int wm   = w >> 1, wn = w & 1;
    const int quad = lane >> 4;       // 0..3
    const int l16  = lane & 15;

    int bid = blockIdx.y * gridDim.x + blockIdx.x;
    const int nwg = gridDim.x * gridDim.y;
    if ((nwg & 7) == 0)
        bid = (bid & 7) * (nwg >> 3) + (bid >> 3);   // bijective chunked swizzle
    const int j0 = (bid % gridDim.x) * 128;
    const int m0 = (bid / gridDim.x) * 128;

    const int srow = lane >> 2;
    const int gseg = ((lane & 3) ^ ((lane >> 3) & 3)) * 8;

    f32x4 acc[4][4] = {};

    if (AEXT) {
        // -------- legacy path (handles fp32 A; single buffer, __syncthreads) --------
        for (int k0 = 0; k0 < K; k0 += 32) {
            if (fmt) {
                #pragma unroll
                for (int i = 0; i < 2; ++i) {
                    const int r0 = w * 32 + i * 16;
                    const float* gp = (const float*)A + (size_t)(m0 + r0 + srow) * K + k0 + gseg;
                    float4 f0 = *(const float4*)gp;
                    float4 f1 = *(const float4*)(gp + 4);
                    union { bf16x8 v; u16 s[8]; } o;
                    o.s[0] = f2b(f0.x); o.s[1] = f2b(f0.y); o.s[2] = f2b(f0.z); o.s[3] = f2b(f0.w);
                    o.s[4] = f2b(f1.x); o.s[5] = f2b(f1.y); o.s[6] = f2b(f1.z); o.s[7] = f2b(f1.w);
                    *(bf16x8*)&As[0][(r0 + srow) * 32 + (lane & 3) * 8] = o.v;
                }
            } else {
                #pragma unroll
                for (int i = 0; i < 2; ++i) {
                    const int r0 = w * 32 + i * 16;
                    const u16* gp = (const u16*)A + (size_t)(m0 + r0 + srow) * K + k0 + gseg;
                    __builtin_amdgcn_global_load_lds(
                        (const __attribute__((address_space(1))) void*)gp,
                        (__attribute__((address_space(3))) void*)&As[0][r0 * 32], 16, 0, 0);
                }
            }
            #pragma unroll
            for (int i = 0; i < 2; ++i) {
                const int r0 = w * 32 + i * 16;
                const u16* gp = BT + (size_t)(j0 + r0 + srow) * K + k0 + gseg;
                __builtin_amdgcn_global_load_lds(
                    (const __attribute__((address_space(1))) void*)gp,
                    (__attribute__((address_space(3))) void*)&Bs[0][r0 * 32], 16, 0, 0);
            }
            __syncthreads();

            bf16x8 af[4], bfr[4];
            #pragma unroll
            for (int mt = 0; mt < 4; ++mt) {
                const int r = wm * 64 + mt * 16 + l16;
                const int slot = quad ^ ((r >> 1) & 3);
                af[mt] = *(const bf16x8*)&As[0][r * 32 + slot * 8];
            }
            #pragma unroll
            for (int nt = 0; nt < 4; ++nt) {
                const int r = wn * 64 + nt * 16 + l16;
                const int slot = quad ^ ((r >> 1) & 3);
                bfr[nt] = *(const bf16x8*)&Bs[0][r * 32 + slot * 8];
            }
            #pragma unroll
            for (int mt = 0; mt < 4; ++mt)
                #pragma unroll
                for (int nt = 0; nt < 4; ++nt)
                    acc[mt][nt] = __builtin_amdgcn_mfma_f32_16x16x32_bf16(
                        af[mt], bfr[nt], acc[mt][nt], 0, 0, 0);
            __syncthreads();
        }
    } else {
        // -------- ring-4 counted-vmcnt pipeline (A, B both bf16) --------
        auto stage = [&](int buf, int tile) {
            const int kk = tile * 32;
            #pragma unroll
            for (int i = 0; i < 2; ++i) {
                const int r0 = w * 32 + i * 16;
                const u16* gp = (const u16*)A + (size_t)(m0 + r0 + srow) * K + kk + gseg;
                __builtin_amdgcn_global_load_lds(
                    (const __attribute__((address_space(1))) void*)gp,
                    (__attribute__((address_space(3))) void*)&As[buf][r0 * 32], 16, 0, 0);
            }
            #pragma unroll
            for (int i = 0; i < 2; ++i) {
                const int r0 = w * 32 + i * 16;
                const u16* gp = BT + (size_t)(j0 + r0 + srow) * K + kk + gseg;
                __builtin_amdgcn_global_load_lds(
                    (const __attribute__((address_space(1))) void*)gp,
                    (__attribute__((address_space(3))) void*)&Bs[buf][r0 * 32], 16, 0, 0);
            }
        };
        auto compute = [&](int buf) {
            bf16x8 af[4], bfr[4];
            #pragma unroll
            for (int mt = 0; mt < 4; ++mt) {
                const int r = wm * 64 + mt * 16 + l16;
                const int slot = quad ^ ((r >> 1) & 3);
                af[mt] = *(const bf16x8*)&As[buf][r * 32 + slot * 8];
            }
            #pragma unroll
            for (int nt = 0; nt < 4; ++nt) {
                const int r = wn * 64 + nt * 16 + l16;
                const int slot = quad ^ ((r >> 1) & 3);
                bfr[nt] = *(const bf16x8*)&Bs[buf][r * 32 + slot * 8];
            }
            __builtin_amdgcn_s_setprio(1);
            #pragma unroll
            for (int mt = 0; mt < 4; ++mt)
                #pragma unroll
                for (int nt = 0; nt < 4; ++nt)
                    acc[mt][nt] = __builtin_amdgcn_mfma_f32_16x16x32_bf16(
                        af[mt], bfr[nt], acc[mt][nt], 0, 0, 0);
            __builtin_amdgcn_s_setprio(0);
        };
        #define GBAR() do {                                   \
            __builtin_amdgcn_sched_barrier(0);                \
            asm volatile("s_barrier" ::: "memory");           \
            __builtin_amdgcn_sched_barrier(0);                \
        } while (0)

        const int nsteps = K >> 5;        // 32-wide K tiles; nsteps % 4 == 0
        // prologue: 3 tiles in flight (12 loads/wave)
        stage(0, 0); stage(1, 1); stage(2, 2);

        int tt = 0;
        for (; tt + 4 < nsteps; tt += 4) {
            stage(3, tt + 3);
            asm volatile("s_waitcnt vmcnt(12)" ::: "memory");
            GBAR(); compute(0); GBAR();
            stage(0, tt + 4);
            asm volatile("s_waitcnt vmcnt(12)" ::: "memory");
            GBAR(); compute(1); GBAR();
            stage(1, tt + 5);
            asm volatile("s_waitcnt vmcnt(12)" ::: "memory");
            GBAR(); compute(2); GBAR();
            stage(2, tt + 6);
            asm volatile("s_waitcnt vmcnt(12)" ::: "memory");
            GBAR(); compute(3); GBAR();
        }
        // tail: tt == nsteps-4; stage last tile, then drain 12 -> 8 -> 4 -> 0
        stage(3, tt + 3);
        asm volatile("s_waitcnt vmcnt(12)" ::: "memory");
        GBAR(); compute(0); GBAR();
        asm volatile("s_waitcnt vmcnt(8)" ::: "memory");
        GBAR(); compute(1); GBAR();
        asm volatile("s_waitcnt vmcnt(4)" ::: "memory");
        GBAR(); compute(2); GBAR();
        asm volatile("s_waitcnt vmcnt(0)" ::: "memory");
        GBAR(); compute(3);
        #undef GBAR
    }

    #pragma unroll
    for (int mt = 0; mt < 4; ++mt) {
        #pragma unroll
        for (int nt = 0; nt < 4; ++nt) {
            const int col = j0 + wn * 64 + nt * 16 + l16;
            float bv = 0.f;
            if (BIAS) bv = fmt ? ((const float*)bias)[col] : b2f(((const u16*)bias)[col]);
            #pragma unroll
            for (int r = 0; r < 4; ++r) {
                const int row = m0 + wm * 64 + mt * 16 + quad * 4 + r;
                float v = acc[mt][nt][r];
                if (BIAS) v += bv;
                if (RELU) v = fmaxf(v, 0.f) + 1e-6f;
                if (CEXT && fmt) ((float*)Cout)[(size_t)row * ldc + col] = v;
                else             ((u16*)Cout)[(size_t)row * ldc + col] = f2b(v);
            }
        }
    }
}

// ---------------------------------------------------------------------------
// Fallback VALU GEMM (proven) — used only if ws_size is too small.
// ---------------------------------------------------------------------------
template<int RELU, int BIAS, int AEXT, int CEXT>
__global__ __launch_bounds__(256)
void gemm_any(const void* __restrict__ A, const void* __restrict__ Bm,
              void* __restrict__ Cout, const void* __restrict__ bias,
              const int* __restrict__ flag,
              int M, int K, int ldb, int bcol0, int ldc)
{
    const int fmt = flag[0];
    __shared__ float As[16][128];
    __shared__ float Bs[16][128];
    const int t  = threadIdx.x;
    const int tx = t & 15, ty = t >> 4;
    const int m0 = blockIdx.y * 128;
    const int j0 = blockIdx.x * 128;
    const int la_row = t >> 1;
    const int la_k   = (t & 1) * 8;
    const int lb_k   = t >> 4;
    const int lb_j   = (t & 15) * 8;

    float acc[8][8];
    #pragma unroll
    for (int i = 0; i < 8; ++i)
        #pragma unroll
        for (int j = 0; j < 8; ++j) acc[i][j] = 0.f;

    for (int k0 = 0; k0 < K; k0 += 16) {
        float af[8], bfv[8];
        if (AEXT && fmt) {
            const float* ap = (const float*)A + (size_t)(m0 + la_row) * K + k0 + la_k;
            float4 a0 = *(const float4*)ap;
            float4 a1 = *(const float4*)(ap + 4);
            af[0] = a0.x; af[1] = a0.y; af[2] = a0.z; af[3] = a0.w;
            af[4] = a1.x; af[5] = a1.y; af[6] = a1.z; af[7] = a1.w;
        } else {
            uint4 av = *(const uint4*)((const u16*)A + (size_t)(m0 + la_row) * K + k0 + la_k);
            unpack8(av, af);
        }
        if (fmt) {
            const float* bp = (const float*)Bm + (size_t)(k0 + lb_k) * ldb + bcol0 + j0 + lb_j;
            float4 b0 = *(const float4*)bp;
            float4 b1 = *(const float4*)(bp + 4);
            bfv[0] = b0.x; bfv[1] = b0.y; bfv[2] = b0.z; bfv[3] = b0.w;
            bfv[4] = b1.x; bfv[5] = b1.y; bfv[6] = b1.z; bfv[7] = b1.w;
        } else {
            uint4 bv = *(const uint4*)((const u16*)Bm + (size_t)(k0 + lb_k) * ldb + bcol0 + j0 + lb_j);
            unpack8(bv, bfv);
        }
        __syncthreads();
        #pragma unroll
        for (int i = 0; i < 8; ++i) As[la_k + i][la_row] = af[i];
        *(float4*)&Bs[lb_k][lb_j]     = make_float4(bfv[0], bfv[1], bfv[2], bfv[3]);
        *(float4*)&Bs[lb_k][lb_j + 4] = make_float4(bfv[4], bfv[5], bfv[6], bfv[7]);
        __syncthreads();
        #pragma unroll
        for (int kk = 0; kk < 16; ++kk) {
            float a[8], b[8];
            *(float4*)&a[0] = *(const float4*)&As[kk][ty * 8];
            *(float4*)&a[4] = *(const float4*)&As[kk][ty * 8 + 4];
            *(float4*)&b[0] = *(const float4*)&Bs[kk][tx * 8];
            *(float4*)&b[4] = *(const float4*)&Bs[kk][tx * 8 + 4];
            #pragma unroll
            for (int i = 0; i < 8; ++i)
                #pragma unroll
                for (int j = 0; j < 8; ++j)
                    acc[i][j] += a[i] * b[j];
        }
    }

    #pragma unroll
    for (int i = 0; i < 8; ++i) {
        const int m = m0 + ty * 8 + i;
        float vals[8];
        #pragma unroll
        for (int j = 0; j < 8; ++j) {
            float v = acc[i][j];
            if (BIAS) {
                const int bi = j0 + tx * 8 + j;
                v += fmt ? ((const float*)bias)[bi] : b2f(((const u16*)bias)[bi]);
            }
            if (RELU) v = fmaxf(v, 0.f) + 1e-6f;
            vals[j] = v;
        }
        if (CEXT && fmt) {
            float* cp = (float*)Cout + (size_t)m * ldc + j0 + tx * 8;
            *(float4*)cp       = make_float4(vals[0], vals[1], vals[2], vals[3]);
            *(float4*)(cp + 4) = make_float4(vals[4], vals[5], vals[6], vals[7]);
        } else {
            union { uint4 v; u16 s[8]; } o;
            #pragma unroll
            for (int j = 0; j < 8; ++j) o.s[j] = f2b(vals[j]);
            *(uint4*)((u16*)Cout + (size_t)m * ldc + j0 + tx * 8) = o.v;
        }
    }
}

// ---------------------------------------------------------------------------
// kv_atomic: kvh += (1/N) sum k*v over 512-row chunk; fused k-channel-mean.
// (R10 version — proven.)
// ---------------------------------------------------------------------------
__global__ __launch_bounds__(256)
void kv_atomic(const u16* __restrict__ k, const u16* __restrict__ v,
               float* __restrict__ kvh, float* __restrict__ km)
{
    __shared__ float kk[32][64];
    __shared__ float vv[32][64];
    const int bh = blockIdx.x;
    const int ch = blockIdx.y;
    const int b = bh >> 4, h = bh & 15;
    const int t = threadIdx.x;
    const int e = t & 63, d0 = (t >> 6) * 16;
    const int lr = t >> 3;            // 0..31: row within round
    const int lc = (t & 7) * 8;       // channel-8 base
    const int n0 = ch * 512;

    float acc[16];
    #pragma unroll
    for (int i = 0; i < 16; ++i) acc[i] = 0.f;
    float ksum[8];
    #pragma unroll
    for (int j = 0; j < 8; ++j) ksum[j] = 0.f;

    const u16* kbase = k + ((size_t)(b * N_ + n0 + lr)) * C_ + h * 64 + lc;
    const u16* vbase = v + ((size_t)(b * N_ + n0 + lr)) * C_ + h * 64 + lc;

    uint4 kreg = *(const uint4*)kbase;
    uint4 vreg = *(const uint4*)vbase;

    for (int rd = 0; rd < 16; ++rd) {
        float kf[8], vf[8];
        unpack8(kreg, kf);
        unpack8(vreg, vf);
        if (rd + 1 < 16) {            // prefetch next round (hides under compute)
            kreg = *(const uint4*)(kbase + (size_t)(rd + 1) * 32 * C_);
            vreg = *(const uint4*)(vbase + (size_t)(rd + 1) * 32 * C_);
        }
        #pragma unroll
        for (int j = 0; j < 8; ++j) ksum[j] += kf[j];
        __syncthreads();              // prior round's LDS reads complete
        #pragma unroll
        for (int j = 0; j < 8; ++j) { kk[lr][lc + j] = kf[j]; vv[lr][lc + j] = vf[j]; }
        __syncthreads();
        #pragma unroll
        for (int r = 0; r < 32; ++r) {
            float ve = vv[r][e];
            #pragma unroll
            for (int i = 0; i < 16; ++i) acc[i] += kk[r][d0 + i] * ve;
        }
    }

    float* dst = kvh + (size_t)bh * 4096;
    #pragma unroll
    for (int i = 0; i < 16; ++i)
        atomicAdd(&dst[(d0 + i) * 64 + e], acc[i] * (1.0f / N_));

    // fused kmean: reduce the 32 row-groups per channel via LDS, 64 atomics/block
    __syncthreads();
    #pragma unroll
    for (int j = 0; j < 8; ++j) kk[lr][lc + j] = ksum[j];
    __syncthreads();
    if (t < 64) {
        float s = 0.f;
        #pragma unroll
        for (int r = 0; r < 32; ++r) s += kk[r][t];
        atomicAdd(&km[b * C_ + h * 64 + t], s * (1.0f / N_));
    }
}

// ---------------------------------------------------------------------------
// att (MFMA): y = (q @ KV_h) * z per 64-row tile x head.
//  - q tile staged via global_load_lds with PRE-SWIZZLED global source
//    (m173: LDS linear, src chunk = lc ^ (row&7)); LDS layout:
//    qs[row*64 + (chunk^(row&7))*8 + (d&7)], chunk = d>>3.
//  - kvh (f32) split into bf16 hi + bf16 residual lo, stored TRANSPOSED
//    (row=e, col=d) with the same swizzle -> two MFMA passes q@hi + q@lo
//    recover ~17 mantissa bits (numerics ~= previous f32 VALU version).
//  - fragment mapping identical to the HW-validated gemm_mfma:
//    A[row][quad*8+j], B[col][quad*8+j], C: col=l16, row=quad*4+r.
//  - z = 1/(q . kmean + eps) computed by 64 lanes, applied in epilogue.
//  - In-place over q is safe: each block reads only its own rows before
//    writing them.
// ---------------------------------------------------------------------------
__global__ __launch_bounds__(256)
void att_kernel(const u16* __restrict__ q, const float* __restrict__ kvh,
                const float* __restrict__ kmean, u16* __restrict__ y)
{
    __shared__ u16 qs[64 * 64];
    __shared__ u16 kvhi[64 * 64];
    __shared__ u16 kvlo[64 * 64];
    __shared__ float kmv[64];
    __shared__ float zs[64];
    const int bh = blockIdx.y;
    const int b = bh >> 4, h = bh & 15;
    const int n0 = blockIdx.x * 64;
    const int t = threadIdx.x;
    const int lane = t & 63, w = t >> 6;
    const int quad = lane >> 4, l16 = lane & 15;

    // ---- stage q tile (bf16) via global_load_lds, pre-swizzled source ----
    #pragma unroll
    for (int i = 0; i < 2; ++i) {
        const int r0 = w * 16 + i * 8;
        const int r  = r0 + (lane >> 3);
        const int lc = lane & 7;
        const int src_chunk = lc ^ (r & 7);
        const u16* gp = q + ((size_t)(b * N_ + n0 + r)) * C_ + h * 64 + src_chunk * 8;
        __builtin_amdgcn_global_load_lds(
            (const __attribute__((address_space(1))) void*)gp,
            (__attribute__((address_space(3))) void*)&qs[r0 * 64], 16, 0, 0);
    }
    // ---- kv -> bf16 hi/lo, transposed + swizzled into LDS ----
    const float* kvsrc = kvh + (size_t)bh * 4096;
    for (int i = t; i < 4096; i += 256) {
        const int d = i >> 6, e = i & 63;
        const float kvv = kvsrc[i];
        const u16 hi = f2b(kvv);
        const u16 lo = f2b(kvv - b2f(hi));
        const int idx = e * 64 + (((d >> 3) ^ (e & 7)) << 3) + (d & 7);
        kvhi[idx] = hi;
        kvlo[idx] = lo;
    }
    if (t < 64) kmv[t] = kmean[b * C_ + h * 64 + t];
    __syncthreads();   // drains vmcnt (global_load_lds) + lgkmcnt

    // ---- z (64 lanes of wave 0) ----
    if (t < 64) {
        float s = 1e-6f;
        #pragma unroll
        for (int d = 0; d < 64; ++d)
            s += b2f(qs[t * 64 + (((d >> 3) ^ (t & 7)) << 3) + (d & 7)]) * kmv[d];
        zs[t] = 1.0f / s;
    }
    __syncthreads();

    // ---- MFMA: wave w -> rows w*16..w*16+15, all 64 e-cols ----
    f32x4 acc[4] = {};
    const int arow = w * 16 + l16;
    #pragma unroll
    for (int kt = 0; kt < 2; ++kt) {
        const int kc = kt * 4;        // chunk base of this 32-wide k-tile
        bf16x8 af = *(const bf16x8*)&qs[arow * 64 + (((kc + quad) ^ (arow & 7)) << 3)];
        #pragma unroll
        for (int nt = 0; nt < 4; ++nt) {
            const int brow = nt * 16 + l16;
            const int bidx = brow * 64 + (((kc + quad) ^ (brow & 7)) << 3);
            bf16x8 bh_ = *(const bf16x8*)&kvhi[bidx];
            acc[nt] = __builtin_amdgcn_mfma_f32_16x16x32_bf16(af, bh_, acc[nt], 0, 0, 0);
            bf16x8 bl_ = *(const bf16x8*)&kvlo[bidx];
            acc[nt] = __builtin_amdgcn_mfma_f32_16x16x32_bf16(af, bl_, acc[nt], 0, 0, 0);
        }
    }

    // ---- epilogue: scale by z, store ----
    #pragma unroll
    for (int nt = 0; nt < 4; ++nt) {
        const int col = nt * 16 + l16;
        #pragma unroll
        for (int r = 0; r < 4; ++r) {
            const int row = w * 16 + quad * 4 + r;
            y[((size_t)(b * N_ + n0 + row)) * C_ + h * 64 + col] =
                f2b(acc[nt][r] * zs[row]);
        }
    }
}

// ---------------------------------------------------------------------------
// Depthwise 5x5 conv over v, add into y — channel-vectorized (uint4 = 8 bf16).
// ---------------------------------------------------------------------------
__global__ __launch_bounds__(256)
void conv_add(const u16* __restrict__ v, const void* __restrict__ w,
              const void* __restrict__ wb, u16* __restrict__ y,
              const int* __restrict__ flag)
{
    __shared__ float wt[25][64];
    __shared__ float bl[64];
    const int fmt = flag[0];
    const int t = threadIdx.x;
    for (int i = t; i < 1600; i += 256) {
        const int tap = i >> 6, c = i & 63;
        const int src = c * 25 + tap;
        wt[tap][c] = fmt ? ((const float*)w)[src] : b2f(((const u16*)w)[src]);
    }
    if (t < 64)
        bl[t] = fmt ? ((const float*)wb)[t] : b2f(((const u16*)wb)[t]);
    __syncthreads();

    const size_t gid = (size_t)blockIdx.x * 256 + t;   // 0 .. 2,097,151
    const int cg = (int)(gid & 127);                   // channel-group (8 ch)
    const int n  = (int)((gid >> 7) & 4095);           // pixel (wave-uniform)
    const int b  = (int)(gid >> 19);
    const int c0 = cg * 8;
    const int cb = c0 & 63;                            // weight channel base
    const int yp = n >> 6, xp = n & 63;

    float acc[8];
    #pragma unroll
    for (int j = 0; j < 8; ++j) acc[j] = bl[cb + j];

    const u16* vbase = v + (size_t)b * N_ * C_ + c0;
    #pragma unroll
    for (int dy = 0; dy < 5; ++dy) {
        const int yy = yp + dy - 2;
        if (yy < 0 || yy >= HW_) continue;
        #pragma unroll
        for (int dx = 0; dx < 5; ++dx) {
            const int xx = xp + dx - 2;
            if (xx < 0 || xx >= HW_) continue;
            uint4 pv = *(const uint4*)(vbase + (size_t)(yy * HW_ + xx) * C_);
            float f[8];
            unpack8(pv, f);
            const int tap = dy * 5 + dx;
            float4 w0 = *(const float4*)&wt[tap][cb];
            float4 w1 = *(const float4*)&wt[tap][cb + 4];
            acc[0] += w0.x * f[0]; acc[1] += w0.y * f[1];
            acc[2] += w0.z * f[2]; acc[3] += w0.w * f[3];
            acc[4] += w1.x * f[4]; acc[5] += w1.y * f[5];
            acc[6] += w1.z * f[6]; acc[7] += w1.w * f[7];
        }
    }

    uint4 yv = *(const uint4*)(y + gid * 8);
    float yf[8];
    unpack8(yv, yf);
    union { uint4 v4; u16 s[8]; } o;
    #pragma unroll
    for (int j = 0; j < 8; ++j) o.s[j] = f2b(yf[j] + acc[j]);
    *(uint4*)(y + gid * 8) = o.v4;
}

extern "C" void kernel_launch(void* const* d_in, const int* in_sizes, int n_in,
                              void* d_out, int out_size, void* d_ws, size_t ws_size,
                              hipStream_t stream)
{
    const void* x     = d_in[0];
    const void* Wq    = d_in[1];
    const void* Wkv   = d_in[2];
    const void* Wproj = d_in[3];
    const void* bproj = d_in[4];
    const void* dwc_w = d_in[5];
    const void* dwc_b = d_in[6];

    char* ws = (char*)d_ws;
    const size_t MI = 1024 * 1024;
    const size_t NEED_FAST = 35 * MI + 17 * 1024;
    // out_size is the fp32 ELEMENT count (R7 finding); gate passes under
    // either convention (elements or bytes).
    const size_t OUT_ELEMS = (size_t)NT_ * C_;

    if (ws_size >= NEED_FAST && (size_t)out_size >= OUT_ELEMS) {
        // ---- fastest path: x pre-converted to bf16 -> all GEMMs use the
        //      ring-4 pipelined path (AEXT=0). ----
        u16*   vbuf  = (u16*)ws;
        u16*   WT    = (u16*)(ws + 32 * MI);
        float* kvh   = (float*)(ws + 34 * MI);
        float* kmean = (float*)(ws + 35 * MI);
        int*   flag  = (int*)(ws + 35 * MI + 16 * 1024);
        u16*   xb    = (u16*)d_out;                       // lower 32 MB of out
        u16*   kq    = (u16*)d_out + (size_t)NT_ * C_;    // upper 32 MB of out
        u16*   ybuf  = (u16*)ws;

        detect_fmt<<<1, 256, 0, stream>>>((const u16*)x, flag);
        zero_f32<<<dim3(1040), 256, 0, stream>>>(kvh, 266240);   // kvh + kmean contiguous
        convert_x<<<dim3(2048), 256, 0, stream>>>(x, xb, flag);

        // v = xb @ Wkv[:, C:]
        transpose_w<<<dim3(16, 16), 256, 0, stream>>>(Wkv, WT, flag, 2 * C_, C_, C_);
        gemm_mfma<0, 0, 0, 0><<<dim3(8, 128), 256, 0, stream>>>(xb, WT, vbuf, nullptr, flag, C_, C_);
        // k = relu(xb @ Wkv[:, :C]) + eps
        transpose_w<<<dim3(16, 16), 256, 0, stream>>>(Wkv, WT, flag, 2 * C_, 0, C_);
        gemm_mfma<1, 0, 0, 0><<<dim3(8, 128), 256, 0, stream>>>(xb, WT, kq, nullptr, flag, C_, C_);

        kv_atomic<<<dim3(64, 8), 256, 0, stream>>>(kq, vbuf, kvh, kmean);

        // q = relu(xb @ Wq) + eps  (overwrites k; k dead, xb disjoint)
        transpose_w<<<dim3(16, 16), 256, 0, stream>>>(Wq, WT, flag, C_, 0, C_);
        gemm_mfma<1, 0, 0, 0><<<dim3(8, 128), 256, 0, stream>>>(xb, WT, kq, nullptr, flag, C_, C_);

        att_kernel<<<dim3(64, 64), 256, 0, stream>>>(kq, kvh, kmean, kq);
        conv_add<<<dim3(8192), 256, 0, stream>>>(vbuf, dwc_w, dwc_b, kq, flag);

        // move y into ws (v dead), then out = y @ Wproj + bproj (fp32 over all of d_out)
        hipMemcpyAsync(ws, kq, (size_t)NT_ * C_ * sizeof(u16), hipMemcpyDeviceToDevice, stream);
        transpose_w<<<dim3(16, 16), 256, 0, stream>>>(Wproj, WT, flag, C_, 0, C_);
        gemm_mfma<0, 1, 0, 1><<<dim3(8, 128), 256, 0, stream>>>(ybuf, WT, d_out, bproj, flag, C_, C_);
    } else if (ws_size >= NEED_FAST) {
        // ---- middle path (MFMA, fp32 A staged in-loop; AEXT=1 legacy) ----
        u16*   vbuf  = (u16*)ws;
        u16*   WT    = (u16*)(ws + 32 * MI);
        float* kvh   = (float*)(ws + 34 * MI);
        float* kmean = (float*)(ws + 35 * MI);
        int*   flag  = (int*)(ws + 35 * MI + 16 * 1024);
        u16*   kq    = (u16*)d_out;
        u16*   ybuf  = (u16*)ws;

        detect_fmt<<<1, 256, 0, stream>>>((const u16*)x, flag);
        zero_f32<<<dim3(1040), 256, 0, stream>>>(kvh, 266240);

        transpose_w<<<dim3(16, 16), 256, 0, stream>>>(Wkv, WT, flag, 2 * C_, C_, C_);
        gemm_mfma<0, 0, 1, 0><<<dim3(8, 128), 256, 0, stream>>>(x, WT, vbuf, nullptr, flag, C_, C_);
        transpose_w<<<dim3(16, 16), 256, 0, stream>>>(Wkv, WT, flag, 2 * C_, 0, C_);
        gemm_mfma<1, 0, 1, 0><<<dim3(8, 128), 256, 0, stream>>>(x, WT, kq, nullptr, flag, C_, C_);

        kv_atomic<<<dim3(64, 8), 256, 0, stream>>>(kq, vbuf, kvh, kmean);

        transpose_w<<<dim3(16, 16), 256, 0, stream>>>(Wq, WT, flag, C_, 0, C_);
        gemm_mfma<1, 0, 1, 0><<<dim3(8, 128), 256, 0, stream>>>(x, WT, kq, nullptr, flag, C_, C_);

        att_kernel<<<dim3(64, 64), 256, 0, stream>>>(kq, kvh, kmean, kq);
        conv_add<<<dim3(8192), 256, 0, stream>>>(vbuf, dwc_w, dwc_b, kq, flag);

        hipMemcpyAsync(ws, d_out, (size_t)NT_ * C_ * sizeof(u16), hipMemcpyDeviceToDevice, stream);
        transpose_w<<<dim3(16, 16), 256, 0, stream>>>(Wproj, WT, flag, C_, 0, C_);
        gemm_mfma<0, 1, 0, 1><<<dim3(8, 128), 256, 0, stream>>>(ybuf, WT, d_out, bproj, flag, C_, C_);
    } else {
        // ---- fallback path (proven) ----
        u16*   vbuf  = (u16*)ws;
        float* kmean = (float*)(ws + 32 * MI);
        float* kvh   = (float*)(ws + 32 * MI + 16 * 1024);
        int*   flag  = (int*)(ws + 32 * MI + 16 * 1024 + 1 * MI);
        u16*   kq    = (u16*)d_out;
        u16*   ybuf  = (u16*)ws;

        detect_fmt<<<1, 256, 0, stream>>>((const u16*)x, flag);
        zero_f32<<<dim3(1040), 256, 0, stream>>>(kmean, 266240);

        gemm_any<0, 0, 1, 0><<<dim3(8, 128), 256, 0, stream>>>(x, Wkv, vbuf, nullptr, flag, NT_, C_, 2 * C_, C_, C_);
        gemm_any<1, 0, 1, 0><<<dim3(8, 128), 256, 0, stream>>>(x, Wkv, kq,   nullptr, flag, NT_, C_, 2 * C_, 0,  C_);

        kv_atomic<<<dim3(64, 8), 256, 0, stream>>>(kq, vbuf, kvh, kmean);

        gemm_any<1, 0, 1, 0><<<dim3(8, 128), 256, 0, stream>>>(x, Wq, kq, nullptr, flag, NT_, C_, C_, 0, C_);

        att_kernel<<<dim3(64, 64), 256, 0, stream>>>(kq, kvh, kmean, kq);
        conv_add<<<dim3(8192), 256, 0, stream>>>(vbuf, dwc_w, dwc_b, kq, flag);

        hipMemcpyAsync(ws, d_out, (size_t)NT_ * C_ * sizeof(u16), hipMemcpyDeviceToDevice, stream);
        gemm_any<0, 1, 0, 1><<<dim3(8, 128), 256, 0, stream>>>(ybuf, Wproj, d_out, bproj, flag, NT_, C_, C_, 0, C_);
    }
}